// Round 11
// baseline (210.434 us; speedup 1.0000x reference)
//
#include <hip/hip_runtime.h>
#include <math.h>

#define BB 2
#define NN 8192
#define CI 64
#define CP 64
#define HH 128
#define WW 128
#define DD 32
#define CF 128
#define SPLITM 8
#define SPLITN 2

typedef __bf16 bf16_t;
typedef __bf16 bf16x8 __attribute__((ext_vector_type(8)));
typedef __bf16 bf16x4 __attribute__((ext_vector_type(4)));
typedef float f32x4 __attribute__((ext_vector_type(4)));

#define SQ_L2E 1.2011224087864498f   /* sqrt(log2(e)) */

__device__ __forceinline__ float fexp2(float x) { return __builtin_amdgcn_exp2f(x); }

__device__ __forceinline__ bf16x8 pack8(float a0,float a1,float a2,float a3,
                                        float b0,float b1,float b2,float b3){
    bf16x8 r;
    r[0]=(bf16_t)a0; r[1]=(bf16_t)a1; r[2]=(bf16_t)a2; r[3]=(bf16_t)a3;
    r[4]=(bf16_t)b0; r[5]=(bf16_t)b1; r[6]=(bf16_t)b2; r[7]=(bf16_t)b3;
    return r;
}

__device__ __forceinline__ bf16x8 ld_av(const bf16_t* p){
    bf16x4 lo = *(const bf16x4*)p;
    bf16x4 hi = *(const bf16x4*)(p + 16);
    bf16x8 r;
    r[0]=lo[0];r[1]=lo[1];r[2]=lo[2];r[3]=lo[3];
    r[4]=hi[0];r[5]=hi[1];r[6]=hi[2];r[7]=hi[3];
    return r;
}

__device__ __forceinline__ void gload_lds16(const void* g, void* l) {
    __builtin_amdgcn_global_load_lds(
        (const __attribute__((address_space(1))) unsigned int*)g,
        (__attribute__((address_space(3))) unsigned int*)l, 16, 0, 0);
}

// transpose img [B][64][HW] -> imgT [B][HW][64]
__global__ __launch_bounds__(256) void k_timg(const float* __restrict__ img, float* __restrict__ imgT) {
    __shared__ float tile[64][65];
    int b = blockIdx.y;
    int pos0 = blockIdx.x * 64;
    int tid = threadIdx.x;
    int q = tid >> 6, r = tid & 63;
    const float* src = img + (size_t)b * CI * (HH * WW);
#pragma unroll
    for (int cc = 0; cc < 16; ++cc) {
        int c = cc * 4 + q;
        tile[c][r] = src[(size_t)c * (HH * WW) + pos0 + r];
    }
    __syncthreads();
    float* dst = imgT + ((size_t)b * (HH * WW) + pos0) * 64;
#pragma unroll
    for (int pp = 0; pp < 16; ++pp) {
        int pos = pp * 4 + q;
        dst[(size_t)pos * 64 + r] = tile[r][pos];
    }
}

// K1: bilinear gather + Q proj (scaled bf16) + V proj (bf16 c-major). float4 LDS dots.
__global__ __launch_bounds__(256) void k_fuse(
    const float* __restrict__ pts_img, const float* __restrict__ imgT,
    const float* __restrict__ pfeat, const float* __restrict__ qkw,
    const float* __restrict__ vw, const float* __restrict__ vb,
    bf16_t* __restrict__ Qb, bf16_t* __restrict__ XVb)
{
    __shared__ __align__(16) float qk_l[DD * 132];
    __shared__ __align__(16) float vw_l[CP * 68];
    __shared__ __align__(16) float fus[16][CF];
    __shared__ bf16_t xvout[64][20];
    int tid = threadIdx.x;
    for (int i = tid; i < DD * CF; i += 256) qk_l[(i >> 7) * 132 + (i & 127)] = qkw[i];
    for (int i = tid; i < CP * CP; i += 256) vw_l[(i >> 6) * 68 + (i & 63)] = vw[i];

    int w = tid >> 6, l = tid & 63;
    int p0 = blockIdx.x * 16;
    int bb = p0 / NN, n0 = p0 % NN;

#pragma unroll
    for (int i = 0; i < 4; ++i) {
        int pt = i * 4 + w;
        int n = n0 + pt;
        float x = pts_img[(size_t)(p0 + pt) * 2 + 0];
        float y = pts_img[(size_t)(p0 + pt) * 2 + 1];
        float ix = (x + 1.f) * 0.5f * WW - 0.5f;
        float iy = (y + 1.f) * 0.5f * HH - 0.5f;
        float x0 = floorf(ix), y0 = floorf(iy);
        float wx1 = ix - x0, wx0 = 1.f - wx1;
        float wy1 = iy - y0, wy0 = 1.f - wy1;
        int xi0 = (int)x0, yi0 = (int)y0;
        const float* base = imgT + (size_t)bb * (HH * WW) * 64 + l;
        float iv = 0.f;
#pragma unroll
        for (int cr = 0; cr < 4; ++cr) {
            int xi = xi0 + (cr & 1), yi = yi0 + (cr >> 1);
            float wgt = ((cr & 1) ? wx1 : wx0) * ((cr >> 1) ? wy1 : wy0);
            bool v = (xi >= 0) & (xi <= WW - 1) & (yi >= 0) & (yi <= HH - 1);
            int cx = min(max(xi, 0), WW - 1), cy = min(max(yi, 0), HH - 1);
            float s = base[((size_t)cy * WW + cx) * 64];
            iv += (v ? s : 0.f) * wgt;
        }
        float pv = pfeat[((size_t)bb * CP + l) * NN + n];
        fus[pt][l] = iv;
        fus[pt][64 + l] = pv;
    }
    __syncthreads();
#pragma unroll
    for (int i = 0; i < 4; ++i) {
        int pt = i * 4 + w;
        int n = n0 + pt;
        {
            int qo = l & 31, kh = l >> 5;
            const float4* qr = (const float4*)&qk_l[qo * 132 + kh * 64];
            const float4* fp = (const float4*)&fus[pt][kh * 64];
            float acc = 0.f;
#pragma unroll
            for (int k = 0; k < 16; ++k) {
                float4 a = qr[k], bq = fp[k];
                acc += a.x * bq.x + a.y * bq.y + a.z * bq.z + a.w * bq.w;
            }
            acc += __shfl_xor(acc, 32);
            if (kh == 0) Qb[((size_t)bb * NN + n) * DD + qo] = (bf16_t)(acc * SQ_L2E);
        }
        {
            const float4* vr = (const float4*)&vw_l[l * 68];
            const float4* fp = (const float4*)&fus[pt][64];
            float acc = vb[l];
#pragma unroll
            for (int k = 0; k < 16; ++k) {
                float4 a = vr[k], bv = fp[k];
                acc += a.x * bv.x + a.y * bv.y + a.z * bv.z + a.w * bv.w;
            }
            xvout[l][pt] = (bf16_t)acc;
        }
    }
    __syncthreads();
    {
        int c = tid >> 2, seg = (tid & 3) * 4;
        bf16x4 vv;
        vv[0] = xvout[c][seg + 0];
        vv[1] = xvout[c][seg + 1];
        vv[2] = xvout[c][seg + 2];
        vv[3] = xvout[c][seg + 3];
        *(bf16x4*)&XVb[((size_t)bb * CP + c) * NN + n0 + seg] = vv;
    }
}

// K2: rowsum[n] = sum_m exp2(E[n,m]) (no max; exp2 headroom). m-split + atomics.
__global__ __launch_bounds__(256) void k_rowsum(
    const bf16_t* __restrict__ Qb, float* __restrict__ rowsumG)
{
    int b = blockIdx.z;
    int n0 = blockIdx.x * 64;
    int mchunk = blockIdx.y * (NN / SPLITM);
    int tid = threadIdx.x;
    int wv = tid >> 6, l = tid & 63;
    int g = l >> 4, c16 = l & 15;
    const bf16x8* Qv = (const bf16x8*)(Qb + (size_t)b * NN * DD);
    f32x4 z = {0.f, 0.f, 0.f, 0.f};

    bf16x8 A0 = Qv[(size_t)(n0 +  0 + c16) * 4 + g];
    bf16x8 A1 = Qv[(size_t)(n0 + 16 + c16) * 4 + g];
    bf16x8 A2 = Qv[(size_t)(n0 + 32 + c16) * 4 + g];
    bf16x8 A3 = Qv[(size_t)(n0 + 48 + c16) * 4 + g];

    float rs[4][4];
#pragma unroll
    for (int a = 0; a < 4; ++a)
#pragma unroll
        for (int r = 0; r < 4; ++r) rs[a][r] = 0.f;

    int mbase = mchunk + wv * 64;
    bf16x8 Bn0 = Qv[(size_t)(mbase +  0 + c16) * 4 + g];
    bf16x8 Bn1 = Qv[(size_t)(mbase + 16 + c16) * 4 + g];
    bf16x8 Bn2 = Qv[(size_t)(mbase + 32 + c16) * 4 + g];
    bf16x8 Bn3 = Qv[(size_t)(mbase + 48 + c16) * 4 + g];

    const int NIT = NN / SPLITM / 256;  // 4
    for (int it = 0; it < NIT; ++it) {
        bf16x8 B0 = Bn0, B1 = Bn1, B2 = Bn2, B3 = Bn3;
        int mnext = mbase + 256;
        if (it + 1 < NIT) {
            Bn0 = Qv[(size_t)(mnext +  0 + c16) * 4 + g];
            Bn1 = Qv[(size_t)(mnext + 16 + c16) * 4 + g];
            Bn2 = Qv[(size_t)(mnext + 32 + c16) * 4 + g];
            Bn3 = Qv[(size_t)(mnext + 48 + c16) * 4 + g];
        }
#define ROWSTEP(Aa, a)                                                        \
        {                                                                     \
            f32x4 e0 = __builtin_amdgcn_mfma_f32_16x16x32_bf16(Aa, B0, z, 0, 0, 0); \
            f32x4 e1 = __builtin_amdgcn_mfma_f32_16x16x32_bf16(Aa, B1, z, 0, 0, 0); \
            f32x4 e2 = __builtin_amdgcn_mfma_f32_16x16x32_bf16(Aa, B2, z, 0, 0, 0); \
            f32x4 e3 = __builtin_amdgcn_mfma_f32_16x16x32_bf16(Aa, B3, z, 0, 0, 0); \
            _Pragma("unroll")                                                 \
            for (int r = 0; r < 4; ++r)                                       \
                rs[a][r] += (fexp2(e0[r]) + fexp2(e1[r])) + (fexp2(e2[r]) + fexp2(e3[r])); \
        }
        ROWSTEP(A0, 0) ROWSTEP(A1, 1) ROWSTEP(A2, 2) ROWSTEP(A3, 3)
#undef ROWSTEP
        mbase = mnext;
    }
#pragma unroll
    for (int a = 0; a < 4; ++a)
#pragma unroll
        for (int r = 0; r < 4; ++r) {
            float v = rs[a][r];
            v += __shfl_xor(v, 1);
            v += __shfl_xor(v, 2);
            v += __shfl_xor(v, 4);
            v += __shfl_xor(v, 8);
            if (c16 == 0)
                atomicAdd(&rowsumG[(size_t)b * NN + n0 + 16 * a + 4 * g + r], v);
        }
}

// K2b: XVs = XV * irs[n] written PRE-SWIZZLED (byte-in-256-chunk ^= (c&7)<<4); irsb = bf16 1/rowsum
__global__ __launch_bounds__(256) void k_scale(
    const float* __restrict__ rowsumG, const bf16_t* __restrict__ XVb,
    bf16_t* __restrict__ XVs, bf16_t* __restrict__ irsb)
{
    int b = blockIdx.y;
    int cq = blockIdx.z;             // c-quarter
    int n = (blockIdx.x * 256 + threadIdx.x) * 4;
    float4 rs = *(const float4*)&rowsumG[(size_t)b * NN + n];
    float ir0 = 1.f / rs.x, ir1 = 1.f / rs.y, ir2 = 1.f / rs.z, ir3 = 1.f / rs.w;
    if (cq == 0) {
        bf16x4 iv;
        iv[0] = (bf16_t)ir0; iv[1] = (bf16_t)ir1; iv[2] = (bf16_t)ir2; iv[3] = (bf16_t)ir3;
        *(bf16x4*)&irsb[(size_t)b * NN + n] = iv;
    }
    const bf16_t* src = XVb + ((size_t)b * CP + cq * 16) * NN + n;
    char* dstbase = (char*)(XVs + ((size_t)b * CP + cq * 16) * NN);
    size_t nb = (size_t)n * 2;
    size_t hi = nb & ~(size_t)255;
    size_t lo = nb & 255;
#pragma unroll
    for (int c = 0; c < 16; ++c) {
        bf16x4 v = *(const bf16x4*)&src[(size_t)c * NN];
        bf16x4 o;
        o[0] = (bf16_t)((float)v[0] * ir0);
        o[1] = (bf16_t)((float)v[1] * ir1);
        o[2] = (bf16_t)((float)v[2] * ir2);
        o[3] = (bf16_t)((float)v[3] * ir3);
        size_t sb = hi | (lo ^ ((size_t)(c & 7) << 4));
        *(bf16x4*)(dstbase + (size_t)c * NN * 2 + sb) = o;
    }
}

// stage one 128-n XVs tile (64 rows x 256B, pre-swizzled source, linear dest) into LDS
__device__ __forceinline__ void stage_tile(const char* xvbase, int n0, char* ldsbuf, int wv, int l) {
#pragma unroll
    for (int k = 0; k < 2; ++k) {
        int R0 = k * 32 + wv * 4;          // 8 waves x 2 calls = rows 0..63
        int row = R0 + (l >> 4);
        const char* g = xvbase + (size_t)row * (NN * 2) + (size_t)n0 * 2 + (size_t)(l & 15) * 16;
        gload_lds16(g, ldsbuf + R0 * 256);
    }
}

// K3: LDS-staged main loop, 2-deep energy pipeline (E for tile t computed in iter t-1).
__global__ __launch_bounds__(512, 4) void k_attn(
    const bf16_t* __restrict__ Qb, const bf16_t* __restrict__ XVs,
    const bf16_t* __restrict__ irsb,
    bf16_t* __restrict__ part, float* __restrict__ cpart)
{
    __shared__ __align__(16) char lds[4 * 64 * 72 * 2];  // 36864B
    __shared__ float csL[4 * 64];

    int b = blockIdx.z;
    int m0 = blockIdx.x * 64;
    int chunk = blockIdx.y;
    int tid = threadIdx.x;
    int wv = tid >> 6, l = tid & 63;
    int g = l >> 4, c16 = l & 15;
    int q4 = wv & 3;        // n-split
    int jh = wv >> 2;       // m-half

    const bf16x8* Qv = (const bf16x8*)(Qb + (size_t)b * NN * DD);
    const char* xvbase = (const char*)(XVs + (size_t)b * CP * NN);
    const bf16_t* irow = irsb + (size_t)b * NN;

    bf16x8 bqA = Qv[(size_t)(m0 + jh * 32 + c16) * 4 + g];
    bf16x8 bqB = Qv[(size_t)(m0 + jh * 32 + 16 + c16) * 4 + g];

    f32x4 z = {0.f, 0.f, 0.f, 0.f};
    f32x4 acc[4][2];
    f32x4 acsA = z, acsB = z;
#pragma unroll
    for (int ci = 0; ci < 4; ++ci) { acc[ci][0] = z; acc[ci][1] = z; }

    const int NT = (NN / SPLITN) / 128;   // 32 tiles
    int nbase = chunk * (NN / SPLITN);

    // prologue: stage tile 0; load tile-0 A-frags; compute E(0); prefetch tile-1 A-frags
    stage_tile(xvbase, nbase, lds, wv, l);
    int nw0 = nbase + q4 * 32;
    bf16x8 aN0 = Qv[(size_t)(nw0 + c16) * 4 + g];
    bf16x8 aN1 = Qv[(size_t)(nw0 + 16 + c16) * 4 + g];
    bf16x8 cifC = ld_av(irow + nw0 + 4 * g);

    f32x4 EA0 = __builtin_amdgcn_mfma_f32_16x16x32_bf16(aN0, bqA, z, 0, 0, 0);
    f32x4 EA1 = __builtin_amdgcn_mfma_f32_16x16x32_bf16(aN1, bqA, z, 0, 0, 0);
    f32x4 EB0 = __builtin_amdgcn_mfma_f32_16x16x32_bf16(aN0, bqB, z, 0, 0, 0);
    f32x4 EB1 = __builtin_amdgcn_mfma_f32_16x16x32_bf16(aN1, bqB, z, 0, 0, 0);

    int nw1 = nbase + 128 + q4 * 32;
    aN0 = Qv[(size_t)(nw1 + c16) * 4 + g];
    aN1 = Qv[(size_t)(nw1 + 16 + c16) * 4 + g];
    bf16x8 cifN = ld_av(irow + nw1 + 4 * g);
    __syncthreads();

    const int swz = (c16 & 7) << 4;
    const int blo = (q4 * 32 + 4 * g) * 2;
    const int lo_off = blo ^ swz;
    const int hi_off = (blo + 32) ^ swz;

    for (int t = 0; t < NT; ++t) {
        char* buf = lds + (t & 1) * 16384;
        if (t + 1 < NT)
            stage_tile(xvbase, nbase + (t + 1) * 128, lds + ((t + 1) & 1) * 16384, wv, l);

        // P for tile t (E computed one iteration ago)
        bf16x8 bpA = pack8(fexp2(EA0[0]), fexp2(EA0[1]), fexp2(EA0[2]), fexp2(EA0[3]),
                           fexp2(EA1[0]), fexp2(EA1[1]), fexp2(EA1[2]), fexp2(EA1[3]));
        bf16x8 bpB = pack8(fexp2(EB0[0]), fexp2(EB0[1]), fexp2(EB0[2]), fexp2(EB0[3]),
                           fexp2(EB1[0]), fexp2(EB1[1]), fexp2(EB1[2]), fexp2(EB1[3]));

        // energy for tile t+1 (A-frags prefetched one iteration ago)
        if (t + 1 < NT) {
            EA0 = __builtin_amdgcn_mfma_f32_16x16x32_bf16(aN0, bqA, z, 0, 0, 0);
            EA1 = __builtin_amdgcn_mfma_f32_16x16x32_bf16(aN1, bqA, z, 0, 0, 0);
            EB0 = __builtin_amdgcn_mfma_f32_16x16x32_bf16(aN0, bqB, z, 0, 0, 0);
            EB1 = __builtin_amdgcn_mfma_f32_16x16x32_bf16(aN1, bqB, z, 0, 0, 0);
        }
        bf16x8 cifU = cifC;
        if (t + 2 < NT) {
            int nw2 = nbase + (t + 2) * 128 + q4 * 32;
            aN0 = Qv[(size_t)(nw2 + c16) * 4 + g];
            aN1 = Qv[(size_t)(nw2 + 16 + c16) * 4 + g];
            cifC = cifN;
            cifN = ld_av(irow + nw2 + 4 * g);
        } else {
            cifC = cifN;
        }

        __builtin_amdgcn_s_setprio(1);
        acsA = __builtin_amdgcn_mfma_f32_16x16x32_bf16(cifU, bpA, acsA, 0, 0, 0);
        acsB = __builtin_amdgcn_mfma_f32_16x16x32_bf16(cifU, bpB, acsB, 0, 0, 0);
#pragma unroll
        for (int ci = 0; ci < 4; ++ci) {
            const char* rp = buf + (16 * ci + c16) * 256;
            bf16x4 lo = *(const bf16x4*)(rp + lo_off);
            bf16x4 hi = *(const bf16x4*)(rp + hi_off);
            bf16x8 xv;
            xv[0]=lo[0];xv[1]=lo[1];xv[2]=lo[2];xv[3]=lo[3];
            xv[4]=hi[0];xv[5]=hi[1];xv[6]=hi[2];xv[7]=hi[3];
            acc[ci][0] = __builtin_amdgcn_mfma_f32_16x16x32_bf16(xv, bpA, acc[ci][0], 0, 0, 0);
            acc[ci][1] = __builtin_amdgcn_mfma_f32_16x16x32_bf16(xv, bpB, acc[ci][1], 0, 0, 0);
        }
        __builtin_amdgcn_s_setprio(0);
        __syncthreads();
    }

    // ---- epilogue ----
    if (l < 16) {
        csL[q4 * 64 + 16 * (2 * jh + 0) + l] = acsA[0];
        csL[q4 * 64 + 16 * (2 * jh + 1) + l] = acsB[0];
    }
    bf16_t* epi = (bf16_t*)lds;   // [4 nsplit][64 cc][72 mm] bf16
#pragma unroll
    for (int ci = 0; ci < 4; ++ci)
#pragma unroll
        for (int jj = 0; jj < 2; ++jj)
#pragma unroll
            for (int r = 0; r < 4; ++r) {
                int cc = 16 * ci + 4 * g + r;
                int mm = jh * 32 + jj * 16 + c16;
                epi[((size_t)q4 * 64 + cc) * 72 + mm] = (bf16_t)acc[ci][jj][r];
            }
    __syncthreads();
    {
        int c = tid >> 3, m8 = (tid & 7) * 8;
        float s[8] = {0.f,0.f,0.f,0.f,0.f,0.f,0.f,0.f};
#pragma unroll
        for (int q = 0; q < 4; ++q) {
            bf16x8 v = *(const bf16x8*)&epi[((size_t)q * 64 + c) * 72 + m8];
#pragma unroll
            for (int i = 0; i < 8; ++i) s[i] += (float)v[i];
        }
        bf16x8 o;
#pragma unroll
        for (int i = 0; i < 8; ++i) o[i] = (bf16_t)s[i];
        *(bf16x8*)&part[(((size_t)chunk * BB + b) * CP + c) * NN + m0 + m8] = o;
    }
    if (tid < 64) {
        float cp = csL[tid] + csL[64 + tid] + csL[128 + tid] + csL[192 + tid];
        cpart[((size_t)chunk * BB + b) * NN + m0 + tid] = cp;
    }
}

// K4: tile kernel: combine partials + L1 renorm + T in LDS + t-conv (f32 VALU) + Y + BN stats.
__global__ __launch_bounds__(256) void k_post(
    const bf16_t* __restrict__ part, const float* __restrict__ cpart,
    const float* __restrict__ pfeat, const float* __restrict__ tw,
    const float* __restrict__ tb, float* __restrict__ Y, float* __restrict__ bnred)
{
    __shared__ float Tl[64][66];    // [c][n]
    __shared__ float twt[64][68];   // [c][o], 16B-aligned rows (272B)
    int tid = threadIdx.x;
    int b = blockIdx.y;
    int n0 = blockIdx.x * 64;
    int nl = tid & 63;
    int grp = tid >> 6;             // 0..3 (== wave id; all lanes of a wave share grp)

    // stage tw transposed: twt[c][o]
    for (int i = tid; i < 64 * 64; i += 256)
        twt[i & 63][i >> 6] = tw[i];

    // phase 1: T = pfeat - (sum part) * ic   (fully coalesced, c-major streams)
    float cs = 0.f;
#pragma unroll
    for (int sp = 0; sp < SPLITN; ++sp)
        cs += cpart[((size_t)sp * BB + b) * NN + n0 + nl];
    float ic = 1.f / (1e-9f + cs);
#pragma unroll
    for (int k = 0; k < 16; ++k) {
        int c = k * 4 + grp;
        float xr = 0.f;
#pragma unroll
        for (int sp = 0; sp < SPLITN; ++sp)
            xr += (float)part[(((size_t)sp * BB + b) * CP + c) * NN + n0 + nl];
        Tl[c][nl] = pfeat[((size_t)b * CP + c) * NN + n0 + nl] - xr * ic;
    }
    __syncthreads();

    // phase 2: thread (nl, grp) -> o in [grp*16, grp*16+16)
    float y0 = tb[grp * 16 + 0], y1 = tb[grp * 16 + 1], y2 = tb[grp * 16 + 2], y3 = tb[grp * 16 + 3];
    float y4 = tb[grp * 16 + 4], y5 = tb[grp * 16 + 5], y6 = tb[grp * 16 + 6], y7 = tb[grp * 16 + 7];
    float y8 = tb[grp * 16 + 8], y9 = tb[grp * 16 + 9], yA = tb[grp * 16 +10], yB = tb[grp * 16 +11];
    float yC = tb[grp * 16 +12], yD = tb[grp * 16 +13], yE = tb[grp * 16 +14], yF = tb[grp * 16 +15];
#pragma unroll 4
    for (int c = 0; c < 64; ++c) {
        float t = Tl[c][nl];
        const float4* wr = (const float4*)&twt[c][grp * 16];
        float4 w0 = wr[0], w1 = wr[1], w2 = wr[2], w3 = wr[3];
        y0 += w0.x * t; y1 += w0.y * t; y2 += w0.z * t; y3 += w0.w * t;
        y4 += w1.x * t; y5 += w1.y * t; y6 += w1.z * t; y7 += w1.w * t;
        y8 += w2.x * t; y9 += w2.y * t; yA += w2.z * t; yB += w2.w * t;
        yC += w3.x * t; yD += w3.y * t; yE += w3.z * t; yF += w3.w * t;
    }
    float* yb = Y + ((size_t)b * CP + grp * 16) * NN + n0 + nl;
    yb[0 * NN] = y0;  yb[1 * NN] = y1;  yb[2 * NN] = y2;  yb[3 * NN] = y3;
    yb[4 * NN] = y4;  yb[5 * NN] = y5;  yb[6 * NN] = y6;  yb[7 * NN] = y7;
    yb[8 * NN] = y8;  yb[9 * NN] = y9;  yb[10 * NN] = yA; yb[11 * NN] = yB;
    yb[12 * NN] = yC; yb[13 * NN] = yD; yb[14 * NN] = yE; yb[15 * NN] = yF;

    // BN partial stats: each wave covers 64 n at fixed o-group -> shfl reduce + lane0 atomics
#define BNRED(YV, OI)                                                          \
    {                                                                          \
        float sv = YV, sq = YV * YV;                                           \
        sv += __shfl_xor(sv, 1);  sq += __shfl_xor(sq, 1);                     \
        sv += __shfl_xor(sv, 2);  sq += __shfl_xor(sq, 2);                     \
        sv += __shfl_xor(sv, 4);  sq += __shfl_xor(sq, 4);                     \
        sv += __shfl_xor(sv, 8);  sq += __shfl_xor(sq, 8);                     \
        sv += __shfl_xor(sv, 16); sq += __shfl_xor(sq, 16);                    \
        sv += __shfl_xor(sv, 32); sq += __shfl_xor(sq, 32);                    \
        if (nl == 0) {                                                         \
            atomicAdd(&bnred[grp * 16 + OI], sv);                              \
            atomicAdd(&bnred[64 + grp * 16 + OI], sq);                         \
        }                                                                      \
    }
    BNRED(y0, 0)  BNRED(y1, 1)  BNRED(y2, 2)  BNRED(y3, 3)
    BNRED(y4, 4)  BNRED(y5, 5)  BNRED(y6, 6)  BNRED(y7, 7)
    BNRED(y8, 8)  BNRED(y9, 9)  BNRED(yA, 10) BNRED(yB, 11)
    BNRED(yC, 12) BNRED(yD, 13) BNRED(yE, 14) BNRED(yF, 15)
#undef BNRED
}

// K5: BN finalize + ReLU + residual (float4 vectorized)
__global__ __launch_bounds__(256) void k_final(
    const float* __restrict__ Y, const float* __restrict__ pfeat,
    const float* __restrict__ gamma, const float* __restrict__ beta,
    const float* __restrict__ bnred, float* __restrict__ out)
{
    int idx4 = blockIdx.x * 256 + threadIdx.x;   // flat over [B][CP][NN]/4
    int o = ((idx4 * 4) / NN) & (CP - 1);
    const float invcnt = 1.f / (float)(BB * NN);
    float mean = bnred[o] * invcnt;
    float var = bnred[64 + o] * invcnt - mean * mean;
    float sc = gamma[o] * rsqrtf(var + 1e-5f);
    float sh = beta[o] - mean * sc;
    float4 y = ((const float4*)Y)[idx4];
    float4 p = ((const float4*)pfeat)[idx4];
    float4 r;
    r.x = p.x + fmaxf(y.x * sc + sh, 0.f);
    r.y = p.y + fmaxf(y.y * sc + sh, 0.f);
    r.z = p.z + fmaxf(y.z * sc + sh, 0.f);
    r.w = p.w + fmaxf(y.w * sc + sh, 0.f);
    ((float4*)out)[idx4] = r;
}

extern "C" void kernel_launch(void* const* d_in, const int* in_sizes, int n_in,
                              void* d_out, int out_size, void* d_ws, size_t ws_size,
                              hipStream_t stream) {
    const float* pts_img = (const float*)d_in[0];
    const float* img     = (const float*)d_in[1];
    const float* pfeat   = (const float*)d_in[2];
    const float* qkw     = (const float*)d_in[3];
    const float* vw      = (const float*)d_in[4];
    const float* vb      = (const float*)d_in[5];
    const float* tw      = (const float*)d_in[6];
    const float* tb      = (const float*)d_in[7];
    const float* gamma   = (const float*)d_in[8];
    const float* beta    = (const float*)d_in[9];

    // workspace layout (bytes), total ~35.3 MB
    char* base = (char*)d_ws;
    bf16_t* Qb      = (bf16_t*)(base);                  // 1,048,576   [B][N][32]
    bf16_t* XVb     = (bf16_t*)(base + 1048576);        // 2,097,152   [B][64][N]
    bf16_t* XVs     = (bf16_t*)(base + 3145728);        // 2,097,152   [B][64][N] irs-scaled, pre-swizzled
    float*  rowsumG = (float*)(base + 5251072);         // 65,536      [B][N]
    float*  bn      = (float*)(base + 5316608);         // 512
    bf16_t* irsb    = (bf16_t*)(base + 5317120);        // 32,768      [B][N] bf16
    float*  cpart   = (float*)(base + 5349888);         // 131,072     [SPLITN][B][N]
    float*  Y       = (float*)(base + 5874176);         // 4,194,304   [B][64][N]
    bf16_t* part    = (bf16_t*)(base + 10068480);       // 4,194,304   [SPLITN][B][64][N] bf16
    float*  imgT    = (float*)(base + 26845696);        // 8,388,608   [B][HW][64]

    hipMemsetAsync(base + 5251072, 0, 66048, stream);  // rowsumG + bn (contiguous)
    k_timg<<<dim3((HH * WW) / 64, BB), 256, 0, stream>>>(img, imgT);
    k_fuse<<<(BB * NN) / 16, 256, 0, stream>>>(pts_img, imgT, pfeat, qkw, vw, vb, Qb, XVb);
    k_rowsum<<<dim3(NN / 64, SPLITM, BB), 256, 0, stream>>>(Qb, rowsumG);
    k_scale<<<dim3(NN / 1024, BB, 4), 256, 0, stream>>>(rowsumG, XVb, XVs, irsb);
    k_attn<<<dim3(NN / 64, SPLITN, BB), 512, 0, stream>>>(Qb, XVs, irsb, part, cpart);
    k_post<<<dim3(NN / 64, BB), 256, 0, stream>>>(part, cpart, pfeat, tw, tb, Y, bn);
    k_final<<<(BB * CP * NN) / 1024, 256, 0, stream>>>(Y, pfeat, gamma, beta, bn, (float*)d_out);
}

// Round 12
// 115.598 us; speedup vs baseline: 1.8204x; 1.8204x over previous
//
#include <hip/hip_runtime.h>
#include <math.h>

#define BB 2
#define NN 8192
#define CI 64
#define CP 64
#define HH 128
#define WW 128
#define DD 32
#define CF 128
#define SPLITM 8
#define SPLITN 2

typedef __bf16 bf16_t;
typedef __bf16 bf16x8 __attribute__((ext_vector_type(8)));
typedef __bf16 bf16x4 __attribute__((ext_vector_type(4)));
typedef float f32x4 __attribute__((ext_vector_type(4)));

#define SQ_L2E 1.2011224087864498f   /* sqrt(log2(e)) */

__device__ __forceinline__ float fexp2(float x) { return __builtin_amdgcn_exp2f(x); }

__device__ __forceinline__ bf16x8 pack8(float a0,float a1,float a2,float a3,
                                        float b0,float b1,float b2,float b3){
    bf16x8 r;
    r[0]=(bf16_t)a0; r[1]=(bf16_t)a1; r[2]=(bf16_t)a2; r[3]=(bf16_t)a3;
    r[4]=(bf16_t)b0; r[5]=(bf16_t)b1; r[6]=(bf16_t)b2; r[7]=(bf16_t)b3;
    return r;
}

__device__ __forceinline__ bf16x8 ld_av(const bf16_t* p){
    bf16x4 lo = *(const bf16x4*)p;
    bf16x4 hi = *(const bf16x4*)(p + 16);
    bf16x8 r;
    r[0]=lo[0];r[1]=lo[1];r[2]=lo[2];r[3]=lo[3];
    r[4]=hi[0];r[5]=hi[1];r[6]=hi[2];r[7]=hi[3];
    return r;
}

__device__ __forceinline__ void gload_lds16(const void* g, void* l) {
    __builtin_amdgcn_global_load_lds(
        (const __attribute__((address_space(1))) unsigned int*)g,
        (__attribute__((address_space(3))) unsigned int*)l, 16, 0, 0);
}

// transpose img [B][64][HW] -> imgT [B][HW][64]
__global__ __launch_bounds__(256) void k_timg(const float* __restrict__ img, float* __restrict__ imgT) {
    __shared__ float tile[64][65];
    int b = blockIdx.y;
    int pos0 = blockIdx.x * 64;
    int tid = threadIdx.x;
    int q = tid >> 6, r = tid & 63;
    const float* src = img + (size_t)b * CI * (HH * WW);
#pragma unroll
    for (int cc = 0; cc < 16; ++cc) {
        int c = cc * 4 + q;
        tile[c][r] = src[(size_t)c * (HH * WW) + pos0 + r];
    }
    __syncthreads();
    float* dst = imgT + ((size_t)b * (HH * WW) + pos0) * 64;
#pragma unroll
    for (int pp = 0; pp < 16; ++pp) {
        int pos = pp * 4 + q;
        dst[(size_t)pos * 64 + r] = tile[r][pos];
    }
}

// K1: bilinear gather + Q proj (scaled bf16) + V proj (bf16 c-major). float4 LDS dots.
__global__ __launch_bounds__(256) void k_fuse(
    const float* __restrict__ pts_img, const float* __restrict__ imgT,
    const float* __restrict__ pfeat, const float* __restrict__ qkw,
    const float* __restrict__ vw, const float* __restrict__ vb,
    bf16_t* __restrict__ Qb, bf16_t* __restrict__ XVb)
{
    __shared__ __align__(16) float qk_l[DD * 132];
    __shared__ __align__(16) float vw_l[CP * 68];
    __shared__ __align__(16) float fus[16][CF];
    __shared__ bf16_t xvout[64][20];
    int tid = threadIdx.x;
    for (int i = tid; i < DD * CF; i += 256) qk_l[(i >> 7) * 132 + (i & 127)] = qkw[i];
    for (int i = tid; i < CP * CP; i += 256) vw_l[(i >> 6) * 68 + (i & 63)] = vw[i];

    int w = tid >> 6, l = tid & 63;
    int p0 = blockIdx.x * 16;
    int bb = p0 / NN, n0 = p0 % NN;

#pragma unroll
    for (int i = 0; i < 4; ++i) {
        int pt = i * 4 + w;
        int n = n0 + pt;
        float x = pts_img[(size_t)(p0 + pt) * 2 + 0];
        float y = pts_img[(size_t)(p0 + pt) * 2 + 1];
        float ix = (x + 1.f) * 0.5f * WW - 0.5f;
        float iy = (y + 1.f) * 0.5f * HH - 0.5f;
        float x0 = floorf(ix), y0 = floorf(iy);
        float wx1 = ix - x0, wx0 = 1.f - wx1;
        float wy1 = iy - y0, wy0 = 1.f - wy1;
        int xi0 = (int)x0, yi0 = (int)y0;
        const float* base = imgT + (size_t)bb * (HH * WW) * 64 + l;
        float iv = 0.f;
#pragma unroll
        for (int cr = 0; cr < 4; ++cr) {
            int xi = xi0 + (cr & 1), yi = yi0 + (cr >> 1);
            float wgt = ((cr & 1) ? wx1 : wx0) * ((cr >> 1) ? wy1 : wy0);
            bool v = (xi >= 0) & (xi <= WW - 1) & (yi >= 0) & (yi <= HH - 1);
            int cx = min(max(xi, 0), WW - 1), cy = min(max(yi, 0), HH - 1);
            float s = base[((size_t)cy * WW + cx) * 64];
            iv += (v ? s : 0.f) * wgt;
        }
        float pv = pfeat[((size_t)bb * CP + l) * NN + n];
        fus[pt][l] = iv;
        fus[pt][64 + l] = pv;
    }
    __syncthreads();
#pragma unroll
    for (int i = 0; i < 4; ++i) {
        int pt = i * 4 + w;
        int n = n0 + pt;
        {
            int qo = l & 31, kh = l >> 5;
            const float4* qr = (const float4*)&qk_l[qo * 132 + kh * 64];
            const float4* fp = (const float4*)&fus[pt][kh * 64];
            float acc = 0.f;
#pragma unroll
            for (int k = 0; k < 16; ++k) {
                float4 a = qr[k], bq = fp[k];
                acc += a.x * bq.x + a.y * bq.y + a.z * bq.z + a.w * bq.w;
            }
            acc += __shfl_xor(acc, 32);
            if (kh == 0) Qb[((size_t)bb * NN + n) * DD + qo] = (bf16_t)(acc * SQ_L2E);
        }
        {
            const float4* vr = (const float4*)&vw_l[l * 68];
            const float4* fp = (const float4*)&fus[pt][64];
            float acc = vb[l];
#pragma unroll
            for (int k = 0; k < 16; ++k) {
                float4 a = vr[k], bv = fp[k];
                acc += a.x * bv.x + a.y * bv.y + a.z * bv.z + a.w * bv.w;
            }
            xvout[l][pt] = (bf16_t)acc;
        }
    }
    __syncthreads();
    {
        int c = tid >> 2, seg = (tid & 3) * 4;
        bf16x4 vv;
        vv[0] = xvout[c][seg + 0];
        vv[1] = xvout[c][seg + 1];
        vv[2] = xvout[c][seg + 2];
        vv[3] = xvout[c][seg + 3];
        *(bf16x4*)&XVb[((size_t)bb * CP + c) * NN + n0 + seg] = vv;
    }
}

// K2: rowsum[n] = sum_m exp2(E[n,m]) (no max; exp2 headroom). m-split + atomics.
__global__ __launch_bounds__(256) void k_rowsum(
    const bf16_t* __restrict__ Qb, float* __restrict__ rowsumG)
{
    int b = blockIdx.z;
    int n0 = blockIdx.x * 64;
    int mchunk = blockIdx.y * (NN / SPLITM);
    int tid = threadIdx.x;
    int wv = tid >> 6, l = tid & 63;
    int g = l >> 4, c16 = l & 15;
    const bf16x8* Qv = (const bf16x8*)(Qb + (size_t)b * NN * DD);
    f32x4 z = {0.f, 0.f, 0.f, 0.f};

    bf16x8 A0 = Qv[(size_t)(n0 +  0 + c16) * 4 + g];
    bf16x8 A1 = Qv[(size_t)(n0 + 16 + c16) * 4 + g];
    bf16x8 A2 = Qv[(size_t)(n0 + 32 + c16) * 4 + g];
    bf16x8 A3 = Qv[(size_t)(n0 + 48 + c16) * 4 + g];

    float rs[4][4];
#pragma unroll
    for (int a = 0; a < 4; ++a)
#pragma unroll
        for (int r = 0; r < 4; ++r) rs[a][r] = 0.f;

    int mbase = mchunk + wv * 64;
    bf16x8 Bn0 = Qv[(size_t)(mbase +  0 + c16) * 4 + g];
    bf16x8 Bn1 = Qv[(size_t)(mbase + 16 + c16) * 4 + g];
    bf16x8 Bn2 = Qv[(size_t)(mbase + 32 + c16) * 4 + g];
    bf16x8 Bn3 = Qv[(size_t)(mbase + 48 + c16) * 4 + g];

    const int NIT = NN / SPLITM / 256;  // 4
    for (int it = 0; it < NIT; ++it) {
        bf16x8 B0 = Bn0, B1 = Bn1, B2 = Bn2, B3 = Bn3;
        int mnext = mbase + 256;
        if (it + 1 < NIT) {
            Bn0 = Qv[(size_t)(mnext +  0 + c16) * 4 + g];
            Bn1 = Qv[(size_t)(mnext + 16 + c16) * 4 + g];
            Bn2 = Qv[(size_t)(mnext + 32 + c16) * 4 + g];
            Bn3 = Qv[(size_t)(mnext + 48 + c16) * 4 + g];
        }
#define ROWSTEP(Aa, a)                                                        \
        {                                                                     \
            f32x4 e0 = __builtin_amdgcn_mfma_f32_16x16x32_bf16(Aa, B0, z, 0, 0, 0); \
            f32x4 e1 = __builtin_amdgcn_mfma_f32_16x16x32_bf16(Aa, B1, z, 0, 0, 0); \
            f32x4 e2 = __builtin_amdgcn_mfma_f32_16x16x32_bf16(Aa, B2, z, 0, 0, 0); \
            f32x4 e3 = __builtin_amdgcn_mfma_f32_16x16x32_bf16(Aa, B3, z, 0, 0, 0); \
            _Pragma("unroll")                                                 \
            for (int r = 0; r < 4; ++r)                                       \
                rs[a][r] += (fexp2(e0[r]) + fexp2(e1[r])) + (fexp2(e2[r]) + fexp2(e3[r])); \
        }
        ROWSTEP(A0, 0) ROWSTEP(A1, 1) ROWSTEP(A2, 2) ROWSTEP(A3, 3)
#undef ROWSTEP
        mbase = mnext;
    }
#pragma unroll
    for (int a = 0; a < 4; ++a)
#pragma unroll
        for (int r = 0; r < 4; ++r) {
            float v = rs[a][r];
            v += __shfl_xor(v, 1);
            v += __shfl_xor(v, 2);
            v += __shfl_xor(v, 4);
            v += __shfl_xor(v, 8);
            if (c16 == 0)
                atomicAdd(&rowsumG[(size_t)b * NN + n0 + 16 * a + 4 * g + r], v);
        }
}

// K2b: XVs = XV * irs[n] written PRE-SWIZZLED (byte-in-256-chunk ^= (c&7)<<4); irsb = bf16 1/rowsum
__global__ __launch_bounds__(256) void k_scale(
    const float* __restrict__ rowsumG, const bf16_t* __restrict__ XVb,
    bf16_t* __restrict__ XVs, bf16_t* __restrict__ irsb)
{
    int b = blockIdx.y;
    int cq = blockIdx.z;             // c-quarter
    int n = (blockIdx.x * 256 + threadIdx.x) * 4;
    float4 rs = *(const float4*)&rowsumG[(size_t)b * NN + n];
    float ir0 = 1.f / rs.x, ir1 = 1.f / rs.y, ir2 = 1.f / rs.z, ir3 = 1.f / rs.w;
    if (cq == 0) {
        bf16x4 iv;
        iv[0] = (bf16_t)ir0; iv[1] = (bf16_t)ir1; iv[2] = (bf16_t)ir2; iv[3] = (bf16_t)ir3;
        *(bf16x4*)&irsb[(size_t)b * NN + n] = iv;
    }
    const bf16_t* src = XVb + ((size_t)b * CP + cq * 16) * NN + n;
    char* dstbase = (char*)(XVs + ((size_t)b * CP + cq * 16) * NN);
    size_t nb = (size_t)n * 2;
    size_t hi = nb & ~(size_t)255;
    size_t lo = nb & 255;
#pragma unroll
    for (int c = 0; c < 16; ++c) {
        bf16x4 v = *(const bf16x4*)&src[(size_t)c * NN];
        bf16x4 o;
        o[0] = (bf16_t)((float)v[0] * ir0);
        o[1] = (bf16_t)((float)v[1] * ir1);
        o[2] = (bf16_t)((float)v[2] * ir2);
        o[3] = (bf16_t)((float)v[3] * ir3);
        size_t sb = hi | (lo ^ ((size_t)(c & 7) << 4));
        *(bf16x4*)(dstbase + (size_t)c * NN * 2 + sb) = o;
    }
}

// stage one 128-n XVs tile (64 rows x 256B, pre-swizzled source, linear dest) into LDS
__device__ __forceinline__ void stage_tile(const char* xvbase, int n0, char* ldsbuf, int wv, int l) {
#pragma unroll
    for (int k = 0; k < 2; ++k) {
        int R0 = k * 32 + wv * 4;          // 8 waves x 2 calls = rows 0..63
        int row = R0 + (l >> 4);
        const char* g = xvbase + (size_t)row * (NN * 2) + (size_t)n0 * 2 + (size_t)(l & 15) * 16;
        gload_lds16(g, ldsbuf + R0 * 256);
    }
}

// K3: LDS-staged main loop, 2-deep energy pipeline (E for tile t computed in iter t-1).
__global__ __launch_bounds__(512, 4) void k_attn(
    const bf16_t* __restrict__ Qb, const bf16_t* __restrict__ XVs,
    const bf16_t* __restrict__ irsb,
    bf16_t* __restrict__ part, float* __restrict__ cpart)
{
    __shared__ __align__(16) char lds[4 * 64 * 72 * 2];  // 36864B
    __shared__ float csL[4 * 64];

    int b = blockIdx.z;
    int m0 = blockIdx.x * 64;
    int chunk = blockIdx.y;
    int tid = threadIdx.x;
    int wv = tid >> 6, l = tid & 63;
    int g = l >> 4, c16 = l & 15;
    int q4 = wv & 3;        // n-split
    int jh = wv >> 2;       // m-half

    const bf16x8* Qv = (const bf16x8*)(Qb + (size_t)b * NN * DD);
    const char* xvbase = (const char*)(XVs + (size_t)b * CP * NN);
    const bf16_t* irow = irsb + (size_t)b * NN;

    bf16x8 bqA = Qv[(size_t)(m0 + jh * 32 + c16) * 4 + g];
    bf16x8 bqB = Qv[(size_t)(m0 + jh * 32 + 16 + c16) * 4 + g];

    f32x4 z = {0.f, 0.f, 0.f, 0.f};
    f32x4 acc[4][2];
    f32x4 acsA = z, acsB = z;
#pragma unroll
    for (int ci = 0; ci < 4; ++ci) { acc[ci][0] = z; acc[ci][1] = z; }

    const int NT = (NN / SPLITN) / 128;   // 32 tiles
    int nbase = chunk * (NN / SPLITN);

    // prologue: stage tile 0; load tile-0 A-frags; compute E(0); prefetch tile-1 A-frags
    stage_tile(xvbase, nbase, lds, wv, l);
    int nw0 = nbase + q4 * 32;
    bf16x8 aN0 = Qv[(size_t)(nw0 + c16) * 4 + g];
    bf16x8 aN1 = Qv[(size_t)(nw0 + 16 + c16) * 4 + g];
    bf16x8 cifC = ld_av(irow + nw0 + 4 * g);

    f32x4 EA0 = __builtin_amdgcn_mfma_f32_16x16x32_bf16(aN0, bqA, z, 0, 0, 0);
    f32x4 EA1 = __builtin_amdgcn_mfma_f32_16x16x32_bf16(aN1, bqA, z, 0, 0, 0);
    f32x4 EB0 = __builtin_amdgcn_mfma_f32_16x16x32_bf16(aN0, bqB, z, 0, 0, 0);
    f32x4 EB1 = __builtin_amdgcn_mfma_f32_16x16x32_bf16(aN1, bqB, z, 0, 0, 0);

    int nw1 = nbase + 128 + q4 * 32;
    aN0 = Qv[(size_t)(nw1 + c16) * 4 + g];
    aN1 = Qv[(size_t)(nw1 + 16 + c16) * 4 + g];
    bf16x8 cifN = ld_av(irow + nw1 + 4 * g);
    __syncthreads();

    const int swz = (c16 & 7) << 4;
    const int blo = (q4 * 32 + 4 * g) * 2;
    const int lo_off = blo ^ swz;
    const int hi_off = (blo + 32) ^ swz;

    for (int t = 0; t < NT; ++t) {
        char* buf = lds + (t & 1) * 16384;
        if (t + 1 < NT)
            stage_tile(xvbase, nbase + (t + 1) * 128, lds + ((t + 1) & 1) * 16384, wv, l);

        // P for tile t (E computed one iteration ago)
        bf16x8 bpA = pack8(fexp2(EA0[0]), fexp2(EA0[1]), fexp2(EA0[2]), fexp2(EA0[3]),
                           fexp2(EA1[0]), fexp2(EA1[1]), fexp2(EA1[2]), fexp2(EA1[3]));
        bf16x8 bpB = pack8(fexp2(EB0[0]), fexp2(EB0[1]), fexp2(EB0[2]), fexp2(EB0[3]),
                           fexp2(EB1[0]), fexp2(EB1[1]), fexp2(EB1[2]), fexp2(EB1[3]));

        // energy for tile t+1 (A-frags prefetched one iteration ago)
        if (t + 1 < NT) {
            EA0 = __builtin_amdgcn_mfma_f32_16x16x32_bf16(aN0, bqA, z, 0, 0, 0);
            EA1 = __builtin_amdgcn_mfma_f32_16x16x32_bf16(aN1, bqA, z, 0, 0, 0);
            EB0 = __builtin_amdgcn_mfma_f32_16x16x32_bf16(aN0, bqB, z, 0, 0, 0);
            EB1 = __builtin_amdgcn_mfma_f32_16x16x32_bf16(aN1, bqB, z, 0, 0, 0);
        }
        bf16x8 cifU = cifC;
        if (t + 2 < NT) {
            int nw2 = nbase + (t + 2) * 128 + q4 * 32;
            aN0 = Qv[(size_t)(nw2 + c16) * 4 + g];
            aN1 = Qv[(size_t)(nw2 + 16 + c16) * 4 + g];
            cifC = cifN;
            cifN = ld_av(irow + nw2 + 4 * g);
        } else {
            cifC = cifN;
        }

        __builtin_amdgcn_s_setprio(1);
        acsA = __builtin_amdgcn_mfma_f32_16x16x32_bf16(cifU, bpA, acsA, 0, 0, 0);
        acsB = __builtin_amdgcn_mfma_f32_16x16x32_bf16(cifU, bpB, acsB, 0, 0, 0);
#pragma unroll
        for (int ci = 0; ci < 4; ++ci) {
            const char* rp = buf + (16 * ci + c16) * 256;
            bf16x4 lo = *(const bf16x4*)(rp + lo_off);
            bf16x4 hi = *(const bf16x4*)(rp + hi_off);
            bf16x8 xv;
            xv[0]=lo[0];xv[1]=lo[1];xv[2]=lo[2];xv[3]=lo[3];
            xv[4]=hi[0];xv[5]=hi[1];xv[6]=hi[2];xv[7]=hi[3];
            acc[ci][0] = __builtin_amdgcn_mfma_f32_16x16x32_bf16(xv, bpA, acc[ci][0], 0, 0, 0);
            acc[ci][1] = __builtin_amdgcn_mfma_f32_16x16x32_bf16(xv, bpB, acc[ci][1], 0, 0, 0);
        }
        __builtin_amdgcn_s_setprio(0);
        __syncthreads();
    }

    // ---- epilogue ----
    if (l < 16) {
        csL[q4 * 64 + 16 * (2 * jh + 0) + l] = acsA[0];
        csL[q4 * 64 + 16 * (2 * jh + 1) + l] = acsB[0];
    }
    bf16_t* epi = (bf16_t*)lds;   // [4 nsplit][64 cc][72 mm] bf16
#pragma unroll
    for (int ci = 0; ci < 4; ++ci)
#pragma unroll
        for (int jj = 0; jj < 2; ++jj)
#pragma unroll
            for (int r = 0; r < 4; ++r) {
                int cc = 16 * ci + 4 * g + r;
                int mm = jh * 32 + jj * 16 + c16;
                epi[((size_t)q4 * 64 + cc) * 72 + mm] = (bf16_t)acc[ci][jj][r];
            }
    __syncthreads();
    {
        int c = tid >> 3, m8 = (tid & 7) * 8;
        float s[8] = {0.f,0.f,0.f,0.f,0.f,0.f,0.f,0.f};
#pragma unroll
        for (int q = 0; q < 4; ++q) {
            bf16x8 v = *(const bf16x8*)&epi[((size_t)q * 64 + c) * 72 + m8];
#pragma unroll
            for (int i = 0; i < 8; ++i) s[i] += (float)v[i];
        }
        bf16x8 o;
#pragma unroll
        for (int i = 0; i < 8; ++i) o[i] = (bf16_t)s[i];
        *(bf16x8*)&part[(((size_t)chunk * BB + b) * CP + c) * NN + m0 + m8] = o;
    }
    if (tid < 64) {
        float cp = csL[tid] + csL[64 + tid] + csL[128 + tid] + csL[192 + tid];
        cpart[((size_t)chunk * BB + b) * NN + m0 + tid] = cp;
    }
}

// K4: tile kernel: combine partials + L1 renorm + T in LDS + t-conv (f32 VALU) + Y. No atomics.
__global__ __launch_bounds__(256) void k_post(
    const bf16_t* __restrict__ part, const float* __restrict__ cpart,
    const float* __restrict__ pfeat, const float* __restrict__ tw,
    const float* __restrict__ tb, float* __restrict__ Y)
{
    __shared__ float Tl[64][66];    // [c][n]
    __shared__ float twt[64][68];   // [c][o], 16B-aligned rows (272B)
    int tid = threadIdx.x;
    int b = blockIdx.y;
    int n0 = blockIdx.x * 64;
    int nl = tid & 63;
    int grp = tid >> 6;             // 0..3

    // stage tw transposed: twt[c][o]
    for (int i = tid; i < 64 * 64; i += 256)
        twt[i & 63][i >> 6] = tw[i];

    // phase 1: T = pfeat - (sum part) * ic   (fully coalesced, c-major streams)
    float cs = 0.f;
#pragma unroll
    for (int sp = 0; sp < SPLITN; ++sp)
        cs += cpart[((size_t)sp * BB + b) * NN + n0 + nl];
    float ic = 1.f / (1e-9f + cs);
#pragma unroll
    for (int k = 0; k < 16; ++k) {
        int c = k * 4 + grp;
        float xr = 0.f;
#pragma unroll
        for (int sp = 0; sp < SPLITN; ++sp)
            xr += (float)part[(((size_t)sp * BB + b) * CP + c) * NN + n0 + nl];
        Tl[c][nl] = pfeat[((size_t)b * CP + c) * NN + n0 + nl] - xr * ic;
    }
    __syncthreads();

    // phase 2: thread (nl, grp) -> o in [grp*16, grp*16+16)
    float y0 = tb[grp * 16 + 0], y1 = tb[grp * 16 + 1], y2 = tb[grp * 16 + 2], y3 = tb[grp * 16 + 3];
    float y4 = tb[grp * 16 + 4], y5 = tb[grp * 16 + 5], y6 = tb[grp * 16 + 6], y7 = tb[grp * 16 + 7];
    float y8 = tb[grp * 16 + 8], y9 = tb[grp * 16 + 9], yA = tb[grp * 16 +10], yB = tb[grp * 16 +11];
    float yC = tb[grp * 16 +12], yD = tb[grp * 16 +13], yE = tb[grp * 16 +14], yF = tb[grp * 16 +15];
#pragma unroll 4
    for (int c = 0; c < 64; ++c) {
        float t = Tl[c][nl];
        const float4* wr = (const float4*)&twt[c][grp * 16];
        float4 w0 = wr[0], w1 = wr[1], w2 = wr[2], w3 = wr[3];
        y0 += w0.x * t; y1 += w0.y * t; y2 += w0.z * t; y3 += w0.w * t;
        y4 += w1.x * t; y5 += w1.y * t; y6 += w1.z * t; y7 += w1.w * t;
        y8 += w2.x * t; y9 += w2.y * t; yA += w2.z * t; yB += w2.w * t;
        yC += w3.x * t; yD += w3.y * t; yE += w3.z * t; yF += w3.w * t;
    }
    float* yb = Y + ((size_t)b * CP + grp * 16) * NN + n0 + nl;
    yb[0 * NN] = y0;  yb[1 * NN] = y1;  yb[2 * NN] = y2;  yb[3 * NN] = y3;
    yb[4 * NN] = y4;  yb[5 * NN] = y5;  yb[6 * NN] = y6;  yb[7 * NN] = y7;
    yb[8 * NN] = y8;  yb[9 * NN] = y9;  yb[10 * NN] = yA; yb[11 * NN] = yB;
    yb[12 * NN] = yC; yb[13 * NN] = yD; yb[14 * NN] = yE; yb[15 * NN] = yF;
}

// K4b: BN stats from Y: block = (n-chunk 2048, o, b); wave reduce + few atomics
__global__ __launch_bounds__(256) void k_bnstat(
    const float* __restrict__ Y, float* __restrict__ bnred)
{
    __shared__ float red[8];
    int tid = threadIdx.x;
    int o = blockIdx.y, b = blockIdx.z;
    const float* row = Y + ((size_t)b * CP + o) * NN + blockIdx.x * 2048 + tid * 8;
    float4 a = *(const float4*)row;
    float4 c4 = *(const float4*)(row + 4);
    float sv = ((a.x + a.y) + (a.z + a.w)) + ((c4.x + c4.y) + (c4.z + c4.w));
    float sq = ((a.x*a.x + a.y*a.y) + (a.z*a.z + a.w*a.w))
             + ((c4.x*c4.x + c4.y*c4.y) + (c4.z*c4.z + c4.w*c4.w));
#pragma unroll
    for (int off = 1; off < 64; off <<= 1) {
        sv += __shfl_xor(sv, off);
        sq += __shfl_xor(sq, off);
    }
    int wv = tid >> 6;
    if ((tid & 63) == 0) { red[wv] = sv; red[4 + wv] = sq; }
    __syncthreads();
    if (tid == 0) {
        atomicAdd(&bnred[o], red[0] + red[1] + red[2] + red[3]);
        atomicAdd(&bnred[64 + o], red[4] + red[5] + red[6] + red[7]);
    }
}

// K5: BN finalize + ReLU + residual (float4 vectorized)
__global__ __launch_bounds__(256) void k_final(
    const float* __restrict__ Y, const float* __restrict__ pfeat,
    const float* __restrict__ gamma, const float* __restrict__ beta,
    const float* __restrict__ bnred, float* __restrict__ out)
{
    int idx4 = blockIdx.x * 256 + threadIdx.x;   // flat over [B][CP][NN]/4
    int o = ((idx4 * 4) / NN) & (CP - 1);
    const float invcnt = 1.f / (float)(BB * NN);
    float mean = bnred[o] * invcnt;
    float var = bnred[64 + o] * invcnt - mean * mean;
    float sc = gamma[o] * rsqrtf(var + 1e-5f);
    float sh = beta[o] - mean * sc;
    float4 y = ((const float4*)Y)[idx4];
    float4 p = ((const float4*)pfeat)[idx4];
    float4 r;
    r.x = p.x + fmaxf(y.x * sc + sh, 0.f);
    r.y = p.y + fmaxf(y.y * sc + sh, 0.f);
    r.z = p.z + fmaxf(y.z * sc + sh, 0.f);
    r.w = p.w + fmaxf(y.w * sc + sh, 0.f);
    ((float4*)out)[idx4] = r;
}

extern "C" void kernel_launch(void* const* d_in, const int* in_sizes, int n_in,
                              void* d_out, int out_size, void* d_ws, size_t ws_size,
                              hipStream_t stream) {
    const float* pts_img = (const float*)d_in[0];
    const float* img     = (const float*)d_in[1];
    const float* pfeat   = (const float*)d_in[2];
    const float* qkw     = (const float*)d_in[3];
    const float* vw      = (const float*)d_in[4];
    const float* vb      = (const float*)d_in[5];
    const float* tw      = (const float*)d_in[6];
    const float* tb      = (const float*)d_in[7];
    const float* gamma   = (const float*)d_in[8];
    const float* beta    = (const float*)d_in[9];

    // workspace layout (bytes), total ~35.3 MB
    char* base = (char*)d_ws;
    bf16_t* Qb      = (bf16_t*)(base);                  // 1,048,576   [B][N][32]
    bf16_t* XVb     = (bf16_t*)(base + 1048576);        // 2,097,152   [B][64][N]
    bf16_t* XVs     = (bf16_t*)(base + 3145728);        // 2,097,152   [B][64][N] irs-scaled, pre-swizzled
    float*  rowsumG = (float*)(base + 5251072);         // 65,536      [B][N]
    float*  bn      = (float*)(base + 5316608);         // 512
    bf16_t* irsb    = (bf16_t*)(base + 5317120);        // 32,768      [B][N] bf16
    float*  cpart   = (float*)(base + 5349888);         // 131,072     [SPLITN][B][N]
    float*  Y       = (float*)(base + 5874176);         // 4,194,304   [B][64][N]
    bf16_t* part    = (bf16_t*)(base + 10068480);       // 4,194,304   [SPLITN][B][64][N] bf16
    float*  imgT    = (float*)(base + 26845696);        // 8,388,608   [B][HW][64]

    hipMemsetAsync(base + 5251072, 0, 66048, stream);  // rowsumG + bn (contiguous)
    k_timg<<<dim3((HH * WW) / 64, BB), 256, 0, stream>>>(img, imgT);
    k_fuse<<<(BB * NN) / 16, 256, 0, stream>>>(pts_img, imgT, pfeat, qkw, vw, vb, Qb, XVb);
    k_rowsum<<<dim3(NN / 64, SPLITM, BB), 256, 0, stream>>>(Qb, rowsumG);
    k_scale<<<dim3(NN / 1024, BB, 4), 256, 0, stream>>>(rowsumG, XVb, XVs, irsb);
    k_attn<<<dim3(NN / 64, SPLITN, BB), 512, 0, stream>>>(Qb, XVs, irsb, part, cpart);
    k_post<<<dim3(NN / 64, BB), 256, 0, stream>>>(part, cpart, pfeat, tw, tb, Y);
    k_bnstat<<<dim3(NN / 2048, CP, BB), 256, 0, stream>>>(Y, bn);
    k_final<<<(BB * CP * NN) / 1024, 256, 0, stream>>>(Y, pfeat, gamma, beta, bn, (float*)d_out);
}

// Round 13
// 113.705 us; speedup vs baseline: 1.8507x; 1.0166x over previous
//
#include <hip/hip_runtime.h>
#include <math.h>

#define BB 2
#define NN 8192
#define CI 64
#define CP 64
#define HH 128
#define WW 128
#define DD 32
#define CF 128
#define SPLITM 8
#define SPLITN 2

typedef __bf16 bf16_t;
typedef __bf16 bf16x8 __attribute__((ext_vector_type(8)));
typedef __bf16 bf16x4 __attribute__((ext_vector_type(4)));
typedef float f32x4 __attribute__((ext_vector_type(4)));

#define SQ_L2E 1.2011224087864498f   /* sqrt(log2(e)) */

__device__ __forceinline__ float fexp2(float x) { return __builtin_amdgcn_exp2f(x); }

__device__ __forceinline__ bf16x8 pack8(float a0,float a1,float a2,float a3,
                                        float b0,float b1,float b2,float b3){
    bf16x8 r;
    r[0]=(bf16_t)a0; r[1]=(bf16_t)a1; r[2]=(bf16_t)a2; r[3]=(bf16_t)a3;
    r[4]=(bf16_t)b0; r[5]=(bf16_t)b1; r[6]=(bf16_t)b2; r[7]=(bf16_t)b3;
    return r;
}

__device__ __forceinline__ bf16x8 ld_av(const bf16_t* p){
    bf16x4 lo = *(const bf16x4*)p;
    bf16x4 hi = *(const bf16x4*)(p + 16);
    bf16x8 r;
    r[0]=lo[0];r[1]=lo[1];r[2]=lo[2];r[3]=lo[3];
    r[4]=hi[0];r[5]=hi[1];r[6]=hi[2];r[7]=hi[3];
    return r;
}

__device__ __forceinline__ void gload_lds16(const void* g, void* l) {
    __builtin_amdgcn_global_load_lds(
        (const __attribute__((address_space(1))) unsigned int*)g,
        (__attribute__((address_space(3))) unsigned int*)l, 16, 0, 0);
}

// transpose img [B][64][HW] -> imgT [B][HW][64]
__global__ __launch_bounds__(256) void k_timg(const float* __restrict__ img, float* __restrict__ imgT) {
    __shared__ float tile[64][65];
    int b = blockIdx.y;
    int pos0 = blockIdx.x * 64;
    int tid = threadIdx.x;
    int q = tid >> 6, r = tid & 63;
    const float* src = img + (size_t)b * CI * (HH * WW);
#pragma unroll
    for (int cc = 0; cc < 16; ++cc) {
        int c = cc * 4 + q;
        tile[c][r] = src[(size_t)c * (HH * WW) + pos0 + r];
    }
    __syncthreads();
    float* dst = imgT + ((size_t)b * (HH * WW) + pos0) * 64;
#pragma unroll
    for (int pp = 0; pp < 16; ++pp) {
        int pos = pp * 4 + q;
        dst[(size_t)pos * 64 + r] = tile[r][pos];
    }
}

// K1: bilinear gather + Q proj (scaled bf16) + V proj (bf16 c-major).
// Weight LDS: power-of-2 row stride + 16B-slot XOR swizzle (slot ^= row&7) -> conflict-free dots.
__global__ __launch_bounds__(256) void k_fuse(
    const float* __restrict__ pts_img, const float* __restrict__ imgT,
    const float* __restrict__ pfeat, const float* __restrict__ qkw,
    const float* __restrict__ vw, const float* __restrict__ vb,
    bf16_t* __restrict__ Qb, bf16_t* __restrict__ XVb)
{
    __shared__ __align__(16) float qk_l[DD * 128];   // [32][128], swizzled 16B slots
    __shared__ __align__(16) float vw_l[CP * 64];    // [64][64], swizzled 16B slots
    __shared__ __align__(16) float fus[16][CF];
    __shared__ bf16_t xvout[64][20];
    int tid = threadIdx.x;
    for (int i = tid; i < DD * CF; i += 256) {
        int r = i >> 7, wd = i & 127;
        qk_l[r * 128 + (((((wd >> 2) ^ (r & 7)) << 2)) | (wd & 3))] = qkw[i];
    }
    for (int i = tid; i < CP * CP; i += 256) {
        int r = i >> 6, wd = i & 63;
        vw_l[r * 64 + (((((wd >> 2) ^ (r & 7)) << 2)) | (wd & 3))] = vw[i];
    }

    int w = tid >> 6, l = tid & 63;
    int p0 = blockIdx.x * 16;
    int bb = p0 / NN, n0 = p0 % NN;

#pragma unroll
    for (int i = 0; i < 4; ++i) {
        int pt = i * 4 + w;
        int n = n0 + pt;
        float x = pts_img[(size_t)(p0 + pt) * 2 + 0];
        float y = pts_img[(size_t)(p0 + pt) * 2 + 1];
        float ix = (x + 1.f) * 0.5f * WW - 0.5f;
        float iy = (y + 1.f) * 0.5f * HH - 0.5f;
        float x0 = floorf(ix), y0 = floorf(iy);
        float wx1 = ix - x0, wx0 = 1.f - wx1;
        float wy1 = iy - y0, wy0 = 1.f - wy1;
        int xi0 = (int)x0, yi0 = (int)y0;
        const float* base = imgT + (size_t)bb * (HH * WW) * 64 + l;
        float iv = 0.f;
#pragma unroll
        for (int cr = 0; cr < 4; ++cr) {
            int xi = xi0 + (cr & 1), yi = yi0 + (cr >> 1);
            float wgt = ((cr & 1) ? wx1 : wx0) * ((cr >> 1) ? wy1 : wy0);
            bool v = (xi >= 0) & (xi <= WW - 1) & (yi >= 0) & (yi <= HH - 1);
            int cx = min(max(xi, 0), WW - 1), cy = min(max(yi, 0), HH - 1);
            float s = base[((size_t)cy * WW + cx) * 64];
            iv += (v ? s : 0.f) * wgt;
        }
        float pv = pfeat[((size_t)bb * CP + l) * NN + n];
        fus[pt][l] = iv;
        fus[pt][64 + l] = pv;
    }
    __syncthreads();
#pragma unroll
    for (int i = 0; i < 4; ++i) {
        int pt = i * 4 + w;
        int n = n0 + pt;
        {
            int qo = l & 31, kh = l >> 5, qs = qo & 7;
            const float* qrow = &qk_l[qo * 128 + kh * 64];
            const float4* fp = (const float4*)&fus[pt][kh * 64];
            float acc = 0.f;
#pragma unroll
            for (int k = 0; k < 16; ++k) {
                float4 a = *(const float4*)&qrow[(k ^ qs) << 2];
                float4 bq = fp[k];
                acc += a.x * bq.x + a.y * bq.y + a.z * bq.z + a.w * bq.w;
            }
            acc += __shfl_xor(acc, 32);
            if (kh == 0) Qb[((size_t)bb * NN + n) * DD + qo] = (bf16_t)(acc * SQ_L2E);
        }
        {
            int vs = l & 7;
            const float* vrow = &vw_l[l * 64];
            const float4* fp2 = (const float4*)&fus[pt][64];
            float acc = vb[l];
#pragma unroll
            for (int k = 0; k < 16; ++k) {
                float4 a = *(const float4*)&vrow[(k ^ vs) << 2];
                float4 bv = fp2[k];
                acc += a.x * bv.x + a.y * bv.y + a.z * bv.z + a.w * bv.w;
            }
            xvout[l][pt] = (bf16_t)acc;
        }
    }
    __syncthreads();
    {
        int c = tid >> 2, seg = (tid & 3) * 4;
        bf16x4 vv;
        vv[0] = xvout[c][seg + 0];
        vv[1] = xvout[c][seg + 1];
        vv[2] = xvout[c][seg + 2];
        vv[3] = xvout[c][seg + 3];
        *(bf16x4*)&XVb[((size_t)bb * CP + c) * NN + n0 + seg] = vv;
    }
}

// K2: rowsum[n] = sum_m exp2(E[n,m]) (no max; exp2 headroom). m-split + atomics.
__global__ __launch_bounds__(256) void k_rowsum(
    const bf16_t* __restrict__ Qb, float* __restrict__ rowsumG)
{
    int b = blockIdx.z;
    int n0 = blockIdx.x * 64;
    int mchunk = blockIdx.y * (NN / SPLITM);
    int tid = threadIdx.x;
    int wv = tid >> 6, l = tid & 63;
    int g = l >> 4, c16 = l & 15;
    const bf16x8* Qv = (const bf16x8*)(Qb + (size_t)b * NN * DD);
    f32x4 z = {0.f, 0.f, 0.f, 0.f};

    bf16x8 A0 = Qv[(size_t)(n0 +  0 + c16) * 4 + g];
    bf16x8 A1 = Qv[(size_t)(n0 + 16 + c16) * 4 + g];
    bf16x8 A2 = Qv[(size_t)(n0 + 32 + c16) * 4 + g];
    bf16x8 A3 = Qv[(size_t)(n0 + 48 + c16) * 4 + g];

    float rs[4][4];
#pragma unroll
    for (int a = 0; a < 4; ++a)
#pragma unroll
        for (int r = 0; r < 4; ++r) rs[a][r] = 0.f;

    int mbase = mchunk + wv * 64;
    bf16x8 Bn0 = Qv[(size_t)(mbase +  0 + c16) * 4 + g];
    bf16x8 Bn1 = Qv[(size_t)(mbase + 16 + c16) * 4 + g];
    bf16x8 Bn2 = Qv[(size_t)(mbase + 32 + c16) * 4 + g];
    bf16x8 Bn3 = Qv[(size_t)(mbase + 48 + c16) * 4 + g];

    const int NIT = NN / SPLITM / 256;  // 4
    for (int it = 0; it < NIT; ++it) {
        bf16x8 B0 = Bn0, B1 = Bn1, B2 = Bn2, B3 = Bn3;
        int mnext = mbase + 256;
        if (it + 1 < NIT) {
            Bn0 = Qv[(size_t)(mnext +  0 + c16) * 4 + g];
            Bn1 = Qv[(size_t)(mnext + 16 + c16) * 4 + g];
            Bn2 = Qv[(size_t)(mnext + 32 + c16) * 4 + g];
            Bn3 = Qv[(size_t)(mnext + 48 + c16) * 4 + g];
        }
#define ROWSTEP(Aa, a)                                                        \
        {                                                                     \
            f32x4 e0 = __builtin_amdgcn_mfma_f32_16x16x32_bf16(Aa, B0, z, 0, 0, 0); \
            f32x4 e1 = __builtin_amdgcn_mfma_f32_16x16x32_bf16(Aa, B1, z, 0, 0, 0); \
            f32x4 e2 = __builtin_amdgcn_mfma_f32_16x16x32_bf16(Aa, B2, z, 0, 0, 0); \
            f32x4 e3 = __builtin_amdgcn_mfma_f32_16x16x32_bf16(Aa, B3, z, 0, 0, 0); \
            _Pragma("unroll")                                                 \
            for (int r = 0; r < 4; ++r)                                       \
                rs[a][r] += (fexp2(e0[r]) + fexp2(e1[r])) + (fexp2(e2[r]) + fexp2(e3[r])); \
        }
        ROWSTEP(A0, 0) ROWSTEP(A1, 1) ROWSTEP(A2, 2) ROWSTEP(A3, 3)
#undef ROWSTEP
        mbase = mnext;
    }
#pragma unroll
    for (int a = 0; a < 4; ++a)
#pragma unroll
        for (int r = 0; r < 4; ++r) {
            float v = rs[a][r];
            v += __shfl_xor(v, 1);
            v += __shfl_xor(v, 2);
            v += __shfl_xor(v, 4);
            v += __shfl_xor(v, 8);
            if (c16 == 0)
                atomicAdd(&rowsumG[(size_t)b * NN + n0 + 16 * a + 4 * g + r], v);
        }
}

// K2b: XVs = XV * irs[n] written PRE-SWIZZLED (byte-in-256-chunk ^= (c&7)<<4); irsb = bf16 1/rowsum
__global__ __launch_bounds__(256) void k_scale(
    const float* __restrict__ rowsumG, const bf16_t* __restrict__ XVb,
    bf16_t* __restrict__ XVs, bf16_t* __restrict__ irsb)
{
    int b = blockIdx.y;
    int cq = blockIdx.z;             // c-quarter
    int n = (blockIdx.x * 256 + threadIdx.x) * 4;
    float4 rs = *(const float4*)&rowsumG[(size_t)b * NN + n];
    float ir0 = 1.f / rs.x, ir1 = 1.f / rs.y, ir2 = 1.f / rs.z, ir3 = 1.f / rs.w;
    if (cq == 0) {
        bf16x4 iv;
        iv[0] = (bf16_t)ir0; iv[1] = (bf16_t)ir1; iv[2] = (bf16_t)ir2; iv[3] = (bf16_t)ir3;
        *(bf16x4*)&irsb[(size_t)b * NN + n] = iv;
    }
    const bf16_t* src = XVb + ((size_t)b * CP + cq * 16) * NN + n;
    char* dstbase = (char*)(XVs + ((size_t)b * CP + cq * 16) * NN);
    size_t nb = (size_t)n * 2;
    size_t hi = nb & ~(size_t)255;
    size_t lo = nb & 255;
#pragma unroll
    for (int c = 0; c < 16; ++c) {
        bf16x4 v = *(const bf16x4*)&src[(size_t)c * NN];
        bf16x4 o;
        o[0] = (bf16_t)((float)v[0] * ir0);
        o[1] = (bf16_t)((float)v[1] * ir1);
        o[2] = (bf16_t)((float)v[2] * ir2);
        o[3] = (bf16_t)((float)v[3] * ir3);
        size_t sb = hi | (lo ^ ((size_t)(c & 7) << 4));
        *(bf16x4*)(dstbase + (size_t)c * NN * 2 + sb) = o;
    }
}

// stage one 128-n XVs tile (64 rows x 256B, pre-swizzled source, linear dest) into LDS
__device__ __forceinline__ void stage_tile(const char* xvbase, int n0, char* ldsbuf, int wv, int l) {
#pragma unroll
    for (int k = 0; k < 2; ++k) {
        int R0 = k * 32 + wv * 4;          // 8 waves x 2 calls = rows 0..63
        int row = R0 + (l >> 4);
        const char* g = xvbase + (size_t)row * (NN * 2) + (size_t)n0 * 2 + (size_t)(l & 15) * 16;
        gload_lds16(g, ldsbuf + R0 * 256);
    }
}

// K3: LDS-staged main loop, 2-deep energy pipeline (E for tile t computed in iter t-1).
__global__ __launch_bounds__(512, 4) void k_attn(
    const bf16_t* __restrict__ Qb, const bf16_t* __restrict__ XVs,
    const bf16_t* __restrict__ irsb,
    bf16_t* __restrict__ part, float* __restrict__ cpart)
{
    __shared__ __align__(16) char lds[4 * 64 * 72 * 2];  // 36864B
    __shared__ float csL[4 * 64];

    int b = blockIdx.z;
    int m0 = blockIdx.x * 64;
    int chunk = blockIdx.y;
    int tid = threadIdx.x;
    int wv = tid >> 6, l = tid & 63;
    int g = l >> 4, c16 = l & 15;
    int q4 = wv & 3;        // n-split
    int jh = wv >> 2;       // m-half

    const bf16x8* Qv = (const bf16x8*)(Qb + (size_t)b * NN * DD);
    const char* xvbase = (const char*)(XVs + (size_t)b * CP * NN);
    const bf16_t* irow = irsb + (size_t)b * NN;

    bf16x8 bqA = Qv[(size_t)(m0 + jh * 32 + c16) * 4 + g];
    bf16x8 bqB = Qv[(size_t)(m0 + jh * 32 + 16 + c16) * 4 + g];

    f32x4 z = {0.f, 0.f, 0.f, 0.f};
    f32x4 acc[4][2];
    f32x4 acsA = z, acsB = z;
#pragma unroll
    for (int ci = 0; ci < 4; ++ci) { acc[ci][0] = z; acc[ci][1] = z; }

    const int NT = (NN / SPLITN) / 128;   // 32 tiles
    int nbase = chunk * (NN / SPLITN);

    // prologue: stage tile 0; load tile-0 A-frags; compute E(0); prefetch tile-1 A-frags
    stage_tile(xvbase, nbase, lds, wv, l);
    int nw0 = nbase + q4 * 32;
    bf16x8 aN0 = Qv[(size_t)(nw0 + c16) * 4 + g];
    bf16x8 aN1 = Qv[(size_t)(nw0 + 16 + c16) * 4 + g];
    bf16x8 cifC = ld_av(irow + nw0 + 4 * g);

    f32x4 EA0 = __builtin_amdgcn_mfma_f32_16x16x32_bf16(aN0, bqA, z, 0, 0, 0);
    f32x4 EA1 = __builtin_amdgcn_mfma_f32_16x16x32_bf16(aN1, bqA, z, 0, 0, 0);
    f32x4 EB0 = __builtin_amdgcn_mfma_f32_16x16x32_bf16(aN0, bqB, z, 0, 0, 0);
    f32x4 EB1 = __builtin_amdgcn_mfma_f32_16x16x32_bf16(aN1, bqB, z, 0, 0, 0);

    int nw1 = nbase + 128 + q4 * 32;
    aN0 = Qv[(size_t)(nw1 + c16) * 4 + g];
    aN1 = Qv[(size_t)(nw1 + 16 + c16) * 4 + g];
    bf16x8 cifN = ld_av(irow + nw1 + 4 * g);
    __syncthreads();

    const int swz = (c16 & 7) << 4;
    const int blo = (q4 * 32 + 4 * g) * 2;
    const int lo_off = blo ^ swz;
    const int hi_off = (blo + 32) ^ swz;

    for (int t = 0; t < NT; ++t) {
        char* buf = lds + (t & 1) * 16384;
        if (t + 1 < NT)
            stage_tile(xvbase, nbase + (t + 1) * 128, lds + ((t + 1) & 1) * 16384, wv, l);

        // P for tile t (E computed one iteration ago)
        bf16x8 bpA = pack8(fexp2(EA0[0]), fexp2(EA0[1]), fexp2(EA0[2]), fexp2(EA0[3]),
                           fexp2(EA1[0]), fexp2(EA1[1]), fexp2(EA1[2]), fexp2(EA1[3]));
        bf16x8 bpB = pack8(fexp2(EB0[0]), fexp2(EB0[1]), fexp2(EB0[2]), fexp2(EB0[3]),
                           fexp2(EB1[0]), fexp2(EB1[1]), fexp2(EB1[2]), fexp2(EB1[3]));

        // energy for tile t+1 (A-frags prefetched one iteration ago)
        if (t + 1 < NT) {
            EA0 = __builtin_amdgcn_mfma_f32_16x16x32_bf16(aN0, bqA, z, 0, 0, 0);
            EA1 = __builtin_amdgcn_mfma_f32_16x16x32_bf16(aN1, bqA, z, 0, 0, 0);
            EB0 = __builtin_amdgcn_mfma_f32_16x16x32_bf16(aN0, bqB, z, 0, 0, 0);
            EB1 = __builtin_amdgcn_mfma_f32_16x16x32_bf16(aN1, bqB, z, 0, 0, 0);
        }
        bf16x8 cifU = cifC;
        if (t + 2 < NT) {
            int nw2 = nbase + (t + 2) * 128 + q4 * 32;
            aN0 = Qv[(size_t)(nw2 + c16) * 4 + g];
            aN1 = Qv[(size_t)(nw2 + 16 + c16) * 4 + g];
            cifC = cifN;
            cifN = ld_av(irow + nw2 + 4 * g);
        } else {
            cifC = cifN;
        }

        __builtin_amdgcn_s_setprio(1);
        acsA = __builtin_amdgcn_mfma_f32_16x16x32_bf16(cifU, bpA, acsA, 0, 0, 0);
        acsB = __builtin_amdgcn_mfma_f32_16x16x32_bf16(cifU, bpB, acsB, 0, 0, 0);
#pragma unroll
        for (int ci = 0; ci < 4; ++ci) {
            const char* rp = buf + (16 * ci + c16) * 256;
            bf16x4 lo = *(const bf16x4*)(rp + lo_off);
            bf16x4 hi = *(const bf16x4*)(rp + hi_off);
            bf16x8 xv;
            xv[0]=lo[0];xv[1]=lo[1];xv[2]=lo[2];xv[3]=lo[3];
            xv[4]=hi[0];xv[5]=hi[1];xv[6]=hi[2];xv[7]=hi[3];
            acc[ci][0] = __builtin_amdgcn_mfma_f32_16x16x32_bf16(xv, bpA, acc[ci][0], 0, 0, 0);
            acc[ci][1] = __builtin_amdgcn_mfma_f32_16x16x32_bf16(xv, bpB, acc[ci][1], 0, 0, 0);
        }
        __builtin_amdgcn_s_setprio(0);
        __syncthreads();
    }

    // ---- epilogue ----
    if (l < 16) {
        csL[q4 * 64 + 16 * (2 * jh + 0) + l] = acsA[0];
        csL[q4 * 64 + 16 * (2 * jh + 1) + l] = acsB[0];
    }
    bf16_t* epi = (bf16_t*)lds;   // [4 nsplit][64 cc][72 mm] bf16
#pragma unroll
    for (int ci = 0; ci < 4; ++ci)
#pragma unroll
        for (int jj = 0; jj < 2; ++jj)
#pragma unroll
            for (int r = 0; r < 4; ++r) {
                int cc = 16 * ci + 4 * g + r;
                int mm = jh * 32 + jj * 16 + c16;
                epi[((size_t)q4 * 64 + cc) * 72 + mm] = (bf16_t)acc[ci][jj][r];
            }
    __syncthreads();
    {
        int c = tid >> 3, m8 = (tid & 7) * 8;
        float s[8] = {0.f,0.f,0.f,0.f,0.f,0.f,0.f,0.f};
#pragma unroll
        for (int q = 0; q < 4; ++q) {
            bf16x8 v = *(const bf16x8*)&epi[((size_t)q * 64 + c) * 72 + m8];
#pragma unroll
            for (int i = 0; i < 8; ++i) s[i] += (float)v[i];
        }
        bf16x8 o;
#pragma unroll
        for (int i = 0; i < 8; ++i) o[i] = (bf16_t)s[i];
        *(bf16x8*)&part[(((size_t)chunk * BB + b) * CP + c) * NN + m0 + m8] = o;
    }
    if (tid < 64) {
        float cp = csL[tid] + csL[64 + tid] + csL[128 + tid] + csL[192 + tid];
        cpart[((size_t)chunk * BB + b) * NN + m0 + tid] = cp;
    }
}

// K4: tile kernel: combine partials + L1 renorm + T in LDS + t-conv (f32 VALU) + Y. No atomics.
__global__ __launch_bounds__(256) void k_post(
    const bf16_t* __restrict__ part, const float* __restrict__ cpart,
    const float* __restrict__ pfeat, const float* __restrict__ tw,
    const float* __restrict__ tb, float* __restrict__ Y)
{
    __shared__ float Tl[64][66];    // [c][n]
    __shared__ float twt[64][68];   // [c][o], 16B-aligned rows (272B)
    int tid = threadIdx.x;
    int b = blockIdx.y;
    int n0 = blockIdx.x * 64;
    int nl = tid & 63;
    int grp = tid >> 6;             // 0..3

    // stage tw transposed: twt[c][o]
    for (int i = tid; i < 64 * 64; i += 256)
        twt[i & 63][i >> 6] = tw[i];

    // phase 1: T = pfeat - (sum part) * ic   (fully coalesced, c-major streams)
    float cs = 0.f;
#pragma unroll
    for (int sp = 0; sp < SPLITN; ++sp)
        cs += cpart[((size_t)sp * BB + b) * NN + n0 + nl];
    float ic = 1.f / (1e-9f + cs);
#pragma unroll
    for (int k = 0; k < 16; ++k) {
        int c = k * 4 + grp;
        float xr = 0.f;
#pragma unroll
        for (int sp = 0; sp < SPLITN; ++sp)
            xr += (float)part[(((size_t)sp * BB + b) * CP + c) * NN + n0 + nl];
        Tl[c][nl] = pfeat[((size_t)b * CP + c) * NN + n0 + nl] - xr * ic;
    }
    __syncthreads();

    // phase 2: thread (nl, grp) -> o in [grp*16, grp*16+16)
    float y0 = tb[grp * 16 + 0], y1 = tb[grp * 16 + 1], y2 = tb[grp * 16 + 2], y3 = tb[grp * 16 + 3];
    float y4 = tb[grp * 16 + 4], y5 = tb[grp * 16 + 5], y6 = tb[grp * 16 + 6], y7 = tb[grp * 16 + 7];
    float y8 = tb[grp * 16 + 8], y9 = tb[grp * 16 + 9], yA = tb[grp * 16 +10], yB = tb[grp * 16 +11];
    float yC = tb[grp * 16 +12], yD = tb[grp * 16 +13], yE = tb[grp * 16 +14], yF = tb[grp * 16 +15];
#pragma unroll 4
    for (int c = 0; c < 64; ++c) {
        float t = Tl[c][nl];
        const float4* wr = (const float4*)&twt[c][grp * 16];
        float4 w0 = wr[0], w1 = wr[1], w2 = wr[2], w3 = wr[3];
        y0 += w0.x * t; y1 += w0.y * t; y2 += w0.z * t; y3 += w0.w * t;
        y4 += w1.x * t; y5 += w1.y * t; y6 += w1.z * t; y7 += w1.w * t;
        y8 += w2.x * t; y9 += w2.y * t; yA += w2.z * t; yB += w2.w * t;
        yC += w3.x * t; yD += w3.y * t; yE += w3.z * t; yF += w3.w * t;
    }
    float* yb = Y + ((size_t)b * CP + grp * 16) * NN + n0 + nl;
    yb[0 * NN] = y0;  yb[1 * NN] = y1;  yb[2 * NN] = y2;  yb[3 * NN] = y3;
    yb[4 * NN] = y4;  yb[5 * NN] = y5;  yb[6 * NN] = y6;  yb[7 * NN] = y7;
    yb[8 * NN] = y8;  yb[9 * NN] = y9;  yb[10 * NN] = yA; yb[11 * NN] = yB;
    yb[12 * NN] = yC; yb[13 * NN] = yD; yb[14 * NN] = yE; yb[15 * NN] = yF;
}

// K4b: BN stats from Y: block = (n-chunk 2048, o, b); wave reduce + few atomics
__global__ __launch_bounds__(256) void k_bnstat(
    const float* __restrict__ Y, float* __restrict__ bnred)
{
    __shared__ float red[8];
    int tid = threadIdx.x;
    int o = blockIdx.y, b = blockIdx.z;
    const float* row = Y + ((size_t)b * CP + o) * NN + blockIdx.x * 2048 + tid * 8;
    float4 a = *(const float4*)row;
    float4 c4 = *(const float4*)(row + 4);
    float sv = ((a.x + a.y) + (a.z + a.w)) + ((c4.x + c4.y) + (c4.z + c4.w));
    float sq = ((a.x*a.x + a.y*a.y) + (a.z*a.z + a.w*a.w))
             + ((c4.x*c4.x + c4.y*c4.y) + (c4.z*c4.z + c4.w*c4.w));
#pragma unroll
    for (int off = 1; off < 64; off <<= 1) {
        sv += __shfl_xor(sv, off);
        sq += __shfl_xor(sq, off);
    }
    int wv = tid >> 6;
    if ((tid & 63) == 0) { red[wv] = sv; red[4 + wv] = sq; }
    __syncthreads();
    if (tid == 0) {
        atomicAdd(&bnred[o], red[0] + red[1] + red[2] + red[3]);
        atomicAdd(&bnred[64 + o], red[4] + red[5] + red[6] + red[7]);
    }
}

// K5: BN finalize + ReLU + residual (float4 vectorized)
__global__ __launch_bounds__(256) void k_final(
    const float* __restrict__ Y, const float* __restrict__ pfeat,
    const float* __restrict__ gamma, const float* __restrict__ beta,
    const float* __restrict__ bnred, float* __restrict__ out)
{
    int idx4 = blockIdx.x * 256 + threadIdx.x;   // flat over [B][CP][NN]/4
    int o = ((idx4 * 4) / NN) & (CP - 1);
    const float invcnt = 1.f / (float)(BB * NN);
    float mean = bnred[o] * invcnt;
    float var = bnred[64 + o] * invcnt - mean * mean;
    float sc = gamma[o] * rsqrtf(var + 1e-5f);
    float sh = beta[o] - mean * sc;
    float4 y = ((const float4*)Y)[idx4];
    float4 p = ((const float4*)pfeat)[idx4];
    float4 r;
    r.x = p.x + fmaxf(y.x * sc + sh, 0.f);
    r.y = p.y + fmaxf(y.y * sc + sh, 0.f);
    r.z = p.z + fmaxf(y.z * sc + sh, 0.f);
    r.w = p.w + fmaxf(y.w * sc + sh, 0.f);
    ((float4*)out)[idx4] = r;
}

extern "C" void kernel_launch(void* const* d_in, const int* in_sizes, int n_in,
                              void* d_out, int out_size, void* d_ws, size_t ws_size,
                              hipStream_t stream) {
    const float* pts_img = (const float*)d_in[0];
    const float* img     = (const float*)d_in[1];
    const float* pfeat   = (const float*)d_in[2];
    const float* qkw     = (const float*)d_in[3];
    const float* vw      = (const float*)d_in[4];
    const float* vb      = (const float*)d_in[5];
    const float* tw      = (const float*)d_in[6];
    const float* tb      = (const float*)d_in[7];
    const float* gamma   = (const float*)d_in[8];
    const float* beta    = (const float*)d_in[9];

    // workspace layout (bytes), total ~35.3 MB
    char* base = (char*)d_ws;
    bf16_t* Qb      = (bf16_t*)(base);                  // 1,048,576   [B][N][32]
    bf16_t* XVb     = (bf16_t*)(base + 1048576);        // 2,097,152   [B][64][N]
    bf16_t* XVs     = (bf16_t*)(base + 3145728);        // 2,097,152   [B][64][N] irs-scaled, pre-swizzled
    float*  rowsumG = (float*)(base + 5251072);         // 65,536      [B][N]
    float*  bn      = (float*)(base + 5316608);         // 512
    bf16_t* irsb    = (bf16_t*)(base + 5317120);        // 32,768      [B][N] bf16
    float*  cpart   = (float*)(base + 5349888);         // 131,072     [SPLITN][B][N]
    float*  Y       = (float*)(base + 5874176);         // 4,194,304   [B][64][N]
    bf16_t* part    = (bf16_t*)(base + 10068480);       // 4,194,304   [SPLITN][B][64][N] bf16
    float*  imgT    = (float*)(base + 26845696);        // 8,388,608   [B][HW][64]

    hipMemsetAsync(base + 5251072, 0, 66048, stream);  // rowsumG + bn (contiguous)
    k_timg<<<dim3((HH * WW) / 64, BB), 256, 0, stream>>>(img, imgT);
    k_fuse<<<(BB * NN) / 16, 256, 0, stream>>>(pts_img, imgT, pfeat, qkw, vw, vb, Qb, XVb);
    k_rowsum<<<dim3(NN / 64, SPLITM, BB), 256, 0, stream>>>(Qb, rowsumG);
    k_scale<<<dim3(NN / 1024, BB, 4), 256, 0, stream>>>(rowsumG, XVb, XVs, irsb);
    k_attn<<<dim3(NN / 64, SPLITN, BB), 512, 0, stream>>>(Qb, XVs, irsb, part, cpart);
    k_post<<<dim3(NN / 64, BB), 256, 0, stream>>>(part, cpart, pfeat, tw, tb, Y);
    k_bnstat<<<dim3(NN / 2048, CP, BB), 256, 0, stream>>>(Y, bn);
    k_final<<<(BB * CP * NN) / 1024, 256, 0, stream>>>(Y, pfeat, gamma, beta, bn, (float*)d_out);
}

// Round 14
// 113.298 us; speedup vs baseline: 1.8573x; 1.0036x over previous
//
#include <hip/hip_runtime.h>
#include <math.h>

#define BB 2
#define NN 8192
#define CI 64
#define CP 64
#define HH 128
#define WW 128
#define DD 32
#define CF 128
#define SPLITM 8
#define SPLITN 2

typedef __bf16 bf16_t;
typedef __bf16 bf16x8 __attribute__((ext_vector_type(8)));
typedef __bf16 bf16x4 __attribute__((ext_vector_type(4)));
typedef float f32x4 __attribute__((ext_vector_type(4)));

#define SQ_L2E 1.2011224087864498f   /* sqrt(log2(e)) */

__device__ __forceinline__ float fexp2(float x) { return __builtin_amdgcn_exp2f(x); }

__device__ __forceinline__ bf16x8 pack8(float a0,float a1,float a2,float a3,
                                        float b0,float b1,float b2,float b3){
    bf16x8 r;
    r[0]=(bf16_t)a0; r[1]=(bf16_t)a1; r[2]=(bf16_t)a2; r[3]=(bf16_t)a3;
    r[4]=(bf16_t)b0; r[5]=(bf16_t)b1; r[6]=(bf16_t)b2; r[7]=(bf16_t)b3;
    return r;
}

__device__ __forceinline__ bf16x8 ld_av(const bf16_t* p){
    bf16x4 lo = *(const bf16x4*)p;
    bf16x4 hi = *(const bf16x4*)(p + 16);
    bf16x8 r;
    r[0]=lo[0];r[1]=lo[1];r[2]=lo[2];r[3]=lo[3];
    r[4]=hi[0];r[5]=hi[1];r[6]=hi[2];r[7]=hi[3];
    return r;
}

__device__ __forceinline__ void gload_lds16(const void* g, void* l) {
    __builtin_amdgcn_global_load_lds(
        (const __attribute__((address_space(1))) unsigned int*)g,
        (__attribute__((address_space(3))) unsigned int*)l, 16, 0, 0);
}

// transpose img [B][64][HW] -> imgT [B][HW][64]
__global__ __launch_bounds__(256) void k_timg(const float* __restrict__ img, float* __restrict__ imgT) {
    __shared__ float tile[64][65];
    int b = blockIdx.y;
    int pos0 = blockIdx.x * 64;
    int tid = threadIdx.x;
    int q = tid >> 6, r = tid & 63;
    const float* src = img + (size_t)b * CI * (HH * WW);
#pragma unroll
    for (int cc = 0; cc < 16; ++cc) {
        int c = cc * 4 + q;
        tile[c][r] = src[(size_t)c * (HH * WW) + pos0 + r];
    }
    __syncthreads();
    float* dst = imgT + ((size_t)b * (HH * WW) + pos0) * 64;
#pragma unroll
    for (int pp = 0; pp < 16; ++pp) {
        int pos = pp * 4 + q;
        dst[(size_t)pos * 64 + r] = tile[r][pos];
    }
}

// K1: bilinear gather + Q proj (scaled bf16) + V proj (bf16 c-major).
// Weight LDS: power-of-2 row stride + 16B-slot XOR swizzle (slot ^= row&7) -> conflict-free dots.
__global__ __launch_bounds__(256) void k_fuse(
    const float* __restrict__ pts_img, const float* __restrict__ imgT,
    const float* __restrict__ pfeat, const float* __restrict__ qkw,
    const float* __restrict__ vw, const float* __restrict__ vb,
    bf16_t* __restrict__ Qb, bf16_t* __restrict__ XVb)
{
    __shared__ __align__(16) float qk_l[DD * 128];   // [32][128], swizzled 16B slots
    __shared__ __align__(16) float vw_l[CP * 64];    // [64][64], swizzled 16B slots
    __shared__ __align__(16) float fus[16][CF];
    __shared__ bf16_t xvout[64][20];
    int tid = threadIdx.x;
    for (int i = tid; i < DD * CF; i += 256) {
        int r = i >> 7, wd = i & 127;
        qk_l[r * 128 + (((((wd >> 2) ^ (r & 7)) << 2)) | (wd & 3))] = qkw[i];
    }
    for (int i = tid; i < CP * CP; i += 256) {
        int r = i >> 6, wd = i & 63;
        vw_l[r * 64 + (((((wd >> 2) ^ (r & 7)) << 2)) | (wd & 3))] = vw[i];
    }

    int w = tid >> 6, l = tid & 63;
    int p0 = blockIdx.x * 16;
    int bb = p0 / NN, n0 = p0 % NN;

#pragma unroll
    for (int i = 0; i < 4; ++i) {
        int pt = i * 4 + w;
        int n = n0 + pt;
        float x = pts_img[(size_t)(p0 + pt) * 2 + 0];
        float y = pts_img[(size_t)(p0 + pt) * 2 + 1];
        float ix = (x + 1.f) * 0.5f * WW - 0.5f;
        float iy = (y + 1.f) * 0.5f * HH - 0.5f;
        float x0 = floorf(ix), y0 = floorf(iy);
        float wx1 = ix - x0, wx0 = 1.f - wx1;
        float wy1 = iy - y0, wy0 = 1.f - wy1;
        int xi0 = (int)x0, yi0 = (int)y0;
        const float* base = imgT + (size_t)bb * (HH * WW) * 64 + l;
        float iv = 0.f;
#pragma unroll
        for (int cr = 0; cr < 4; ++cr) {
            int xi = xi0 + (cr & 1), yi = yi0 + (cr >> 1);
            float wgt = ((cr & 1) ? wx1 : wx0) * ((cr >> 1) ? wy1 : wy0);
            bool v = (xi >= 0) & (xi <= WW - 1) & (yi >= 0) & (yi <= HH - 1);
            int cx = min(max(xi, 0), WW - 1), cy = min(max(yi, 0), HH - 1);
            float s = base[((size_t)cy * WW + cx) * 64];
            iv += (v ? s : 0.f) * wgt;
        }
        float pv = pfeat[((size_t)bb * CP + l) * NN + n];
        fus[pt][l] = iv;
        fus[pt][64 + l] = pv;
    }
    __syncthreads();
#pragma unroll
    for (int i = 0; i < 4; ++i) {
        int pt = i * 4 + w;
        int n = n0 + pt;
        {
            int qo = l & 31, kh = l >> 5, qs = qo & 7;
            const float* qrow = &qk_l[qo * 128 + kh * 64];
            const float4* fp = (const float4*)&fus[pt][kh * 64];
            float acc = 0.f;
#pragma unroll
            for (int k = 0; k < 16; ++k) {
                float4 a = *(const float4*)&qrow[(k ^ qs) << 2];
                float4 bq = fp[k];
                acc += a.x * bq.x + a.y * bq.y + a.z * bq.z + a.w * bq.w;
            }
            acc += __shfl_xor(acc, 32);
            if (kh == 0) Qb[((size_t)bb * NN + n) * DD + qo] = (bf16_t)(acc * SQ_L2E);
        }
        {
            int vs = l & 7;
            const float* vrow = &vw_l[l * 64];
            const float4* fp2 = (const float4*)&fus[pt][64];
            float acc = vb[l];
#pragma unroll
            for (int k = 0; k < 16; ++k) {
                float4 a = *(const float4*)&vrow[(k ^ vs) << 2];
                float4 bv = fp2[k];
                acc += a.x * bv.x + a.y * bv.y + a.z * bv.z + a.w * bv.w;
            }
            xvout[l][pt] = (bf16_t)acc;
        }
    }
    __syncthreads();
    {
        int c = tid >> 2, seg = (tid & 3) * 4;
        bf16x4 vv;
        vv[0] = xvout[c][seg + 0];
        vv[1] = xvout[c][seg + 1];
        vv[2] = xvout[c][seg + 2];
        vv[3] = xvout[c][seg + 3];
        *(bf16x4*)&XVb[((size_t)bb * CP + c) * NN + n0 + seg] = vv;
    }
}

// K2: rowsum[n] = sum_m exp2(E[n,m]) (no max; exp2 headroom). m-split + atomics.
__global__ __launch_bounds__(256) void k_rowsum(
    const bf16_t* __restrict__ Qb, float* __restrict__ rowsumG)
{
    int b = blockIdx.z;
    int n0 = blockIdx.x * 64;
    int mchunk = blockIdx.y * (NN / SPLITM);
    int tid = threadIdx.x;
    int wv = tid >> 6, l = tid & 63;
    int g = l >> 4, c16 = l & 15;
    const bf16x8* Qv = (const bf16x8*)(Qb + (size_t)b * NN * DD);
    f32x4 z = {0.f, 0.f, 0.f, 0.f};

    bf16x8 A0 = Qv[(size_t)(n0 +  0 + c16) * 4 + g];
    bf16x8 A1 = Qv[(size_t)(n0 + 16 + c16) * 4 + g];
    bf16x8 A2 = Qv[(size_t)(n0 + 32 + c16) * 4 + g];
    bf16x8 A3 = Qv[(size_t)(n0 + 48 + c16) * 4 + g];

    float rs[4][4];
#pragma unroll
    for (int a = 0; a < 4; ++a)
#pragma unroll
        for (int r = 0; r < 4; ++r) rs[a][r] = 0.f;

    int mbase = mchunk + wv * 64;
    bf16x8 Bn0 = Qv[(size_t)(mbase +  0 + c16) * 4 + g];
    bf16x8 Bn1 = Qv[(size_t)(mbase + 16 + c16) * 4 + g];
    bf16x8 Bn2 = Qv[(size_t)(mbase + 32 + c16) * 4 + g];
    bf16x8 Bn3 = Qv[(size_t)(mbase + 48 + c16) * 4 + g];

    const int NIT = NN / SPLITM / 256;  // 4
    for (int it = 0; it < NIT; ++it) {
        bf16x8 B0 = Bn0, B1 = Bn1, B2 = Bn2, B3 = Bn3;
        int mnext = mbase + 256;
        if (it + 1 < NIT) {
            Bn0 = Qv[(size_t)(mnext +  0 + c16) * 4 + g];
            Bn1 = Qv[(size_t)(mnext + 16 + c16) * 4 + g];
            Bn2 = Qv[(size_t)(mnext + 32 + c16) * 4 + g];
            Bn3 = Qv[(size_t)(mnext + 48 + c16) * 4 + g];
        }
#define ROWSTEP(Aa, a)                                                        \
        {                                                                     \
            f32x4 e0 = __builtin_amdgcn_mfma_f32_16x16x32_bf16(Aa, B0, z, 0, 0, 0); \
            f32x4 e1 = __builtin_amdgcn_mfma_f32_16x16x32_bf16(Aa, B1, z, 0, 0, 0); \
            f32x4 e2 = __builtin_amdgcn_mfma_f32_16x16x32_bf16(Aa, B2, z, 0, 0, 0); \
            f32x4 e3 = __builtin_amdgcn_mfma_f32_16x16x32_bf16(Aa, B3, z, 0, 0, 0); \
            _Pragma("unroll")                                                 \
            for (int r = 0; r < 4; ++r)                                       \
                rs[a][r] += (fexp2(e0[r]) + fexp2(e1[r])) + (fexp2(e2[r]) + fexp2(e3[r])); \
        }
        ROWSTEP(A0, 0) ROWSTEP(A1, 1) ROWSTEP(A2, 2) ROWSTEP(A3, 3)
#undef ROWSTEP
        mbase = mnext;
    }
#pragma unroll
    for (int a = 0; a < 4; ++a)
#pragma unroll
        for (int r = 0; r < 4; ++r) {
            float v = rs[a][r];
            v += __shfl_xor(v, 1);
            v += __shfl_xor(v, 2);
            v += __shfl_xor(v, 4);
            v += __shfl_xor(v, 8);
            if (c16 == 0)
                atomicAdd(&rowsumG[(size_t)b * NN + n0 + 16 * a + 4 * g + r], v);
        }
}

// K2b: XVs = XV * irs[n] written PRE-SWIZZLED (byte-in-256-chunk ^= (c&7)<<4); irsb = bf16 1/rowsum
__global__ __launch_bounds__(256) void k_scale(
    const float* __restrict__ rowsumG, const bf16_t* __restrict__ XVb,
    bf16_t* __restrict__ XVs, bf16_t* __restrict__ irsb)
{
    int b = blockIdx.y;
    int cq = blockIdx.z;             // c-quarter
    int n = (blockIdx.x * 256 + threadIdx.x) * 4;
    float4 rs = *(const float4*)&rowsumG[(size_t)b * NN + n];
    float ir0 = 1.f / rs.x, ir1 = 1.f / rs.y, ir2 = 1.f / rs.z, ir3 = 1.f / rs.w;
    if (cq == 0) {
        bf16x4 iv;
        iv[0] = (bf16_t)ir0; iv[1] = (bf16_t)ir1; iv[2] = (bf16_t)ir2; iv[3] = (bf16_t)ir3;
        *(bf16x4*)&irsb[(size_t)b * NN + n] = iv;
    }
    const bf16_t* src = XVb + ((size_t)b * CP + cq * 16) * NN + n;
    char* dstbase = (char*)(XVs + ((size_t)b * CP + cq * 16) * NN);
    size_t nb = (size_t)n * 2;
    size_t hi = nb & ~(size_t)255;
    size_t lo = nb & 255;
#pragma unroll
    for (int c = 0; c < 16; ++c) {
        bf16x4 v = *(const bf16x4*)&src[(size_t)c * NN];
        bf16x4 o;
        o[0] = (bf16_t)((float)v[0] * ir0);
        o[1] = (bf16_t)((float)v[1] * ir1);
        o[2] = (bf16_t)((float)v[2] * ir2);
        o[3] = (bf16_t)((float)v[3] * ir3);
        size_t sb = hi | (lo ^ ((size_t)(c & 7) << 4));
        *(bf16x4*)(dstbase + (size_t)c * NN * 2 + sb) = o;
    }
}

// stage one 128-n XVs tile (64 rows x 256B, pre-swizzled source, linear dest) into LDS
__device__ __forceinline__ void stage_tile(const char* xvbase, int n0, char* ldsbuf, int wv, int l) {
#pragma unroll
    for (int k = 0; k < 2; ++k) {
        int R0 = k * 32 + wv * 4;          // 8 waves x 2 calls = rows 0..63
        int row = R0 + (l >> 4);
        const char* g = xvbase + (size_t)row * (NN * 2) + (size_t)n0 * 2 + (size_t)(l & 15) * 16;
        gload_lds16(g, ldsbuf + R0 * 256);
    }
}

// K3: LDS-staged main loop, 2-deep energy pipeline + counted-vmcnt barrier (T4).
// Per-iter VMEM order per wave: [2x gload_lds][2x aN][2x cif] -> vmcnt(4) before
// s_barrier guarantees the gload_lds landed while prefetch loads stay in flight.
__global__ __launch_bounds__(512, 4) void k_attn(
    const bf16_t* __restrict__ Qb, const bf16_t* __restrict__ XVs,
    const bf16_t* __restrict__ irsb,
    bf16_t* __restrict__ part, float* __restrict__ cpart)
{
    __shared__ __align__(16) char lds[4 * 64 * 72 * 2];  // 36864B
    __shared__ float csL[4 * 64];

    int b = blockIdx.z;
    int m0 = blockIdx.x * 64;
    int chunk = blockIdx.y;
    int tid = threadIdx.x;
    int wv = tid >> 6, l = tid & 63;
    int g = l >> 4, c16 = l & 15;
    int q4 = wv & 3;        // n-split
    int jh = wv >> 2;       // m-half

    const bf16x8* Qv = (const bf16x8*)(Qb + (size_t)b * NN * DD);
    const char* xvbase = (const char*)(XVs + (size_t)b * CP * NN);
    const bf16_t* irow = irsb + (size_t)b * NN;

    bf16x8 bqA = Qv[(size_t)(m0 + jh * 32 + c16) * 4 + g];
    bf16x8 bqB = Qv[(size_t)(m0 + jh * 32 + 16 + c16) * 4 + g];

    f32x4 z = {0.f, 0.f, 0.f, 0.f};
    f32x4 acc[4][2];
    f32x4 acsA = z, acsB = z;
#pragma unroll
    for (int ci = 0; ci < 4; ++ci) { acc[ci][0] = z; acc[ci][1] = z; }

    const int NT = (NN / SPLITN) / 128;   // 32 tiles
    int nbase = chunk * (NN / SPLITN);

    // prologue: stage tile 0; load tile-0 A-frags; compute E(0); prefetch tile-1 A-frags
    stage_tile(xvbase, nbase, lds, wv, l);
    int nw0 = nbase + q4 * 32;
    bf16x8 aN0 = Qv[(size_t)(nw0 + c16) * 4 + g];
    bf16x8 aN1 = Qv[(size_t)(nw0 + 16 + c16) * 4 + g];
    bf16x8 cifC = ld_av(irow + nw0 + 4 * g);

    f32x4 EA0 = __builtin_amdgcn_mfma_f32_16x16x32_bf16(aN0, bqA, z, 0, 0, 0);
    f32x4 EA1 = __builtin_amdgcn_mfma_f32_16x16x32_bf16(aN1, bqA, z, 0, 0, 0);
    f32x4 EB0 = __builtin_amdgcn_mfma_f32_16x16x32_bf16(aN0, bqB, z, 0, 0, 0);
    f32x4 EB1 = __builtin_amdgcn_mfma_f32_16x16x32_bf16(aN1, bqB, z, 0, 0, 0);

    int nw1 = nbase + 128 + q4 * 32;
    aN0 = Qv[(size_t)(nw1 + c16) * 4 + g];
    aN1 = Qv[(size_t)(nw1 + 16 + c16) * 4 + g];
    bf16x8 cifN = ld_av(irow + nw1 + 4 * g);
    __syncthreads();   // full drain once at start (tile 0 staged)

    const int swz = (c16 & 7) << 4;
    const int blo = (q4 * 32 + 4 * g) * 2;
    const int lo_off = blo ^ swz;
    const int hi_off = (blo + 32) ^ swz;

    for (int t = 0; t < NT; ++t) {
        char* buf = lds + (t & 1) * 16384;
        if (t + 1 < NT)
            stage_tile(xvbase, nbase + (t + 1) * 128, lds + ((t + 1) & 1) * 16384, wv, l);

        // P for tile t (E computed one iteration ago)
        bf16x8 bpA = pack8(fexp2(EA0[0]), fexp2(EA0[1]), fexp2(EA0[2]), fexp2(EA0[3]),
                           fexp2(EA1[0]), fexp2(EA1[1]), fexp2(EA1[2]), fexp2(EA1[3]));
        bf16x8 bpB = pack8(fexp2(EB0[0]), fexp2(EB0[1]), fexp2(EB0[2]), fexp2(EB0[3]),
                           fexp2(EB1[0]), fexp2(EB1[1]), fexp2(EB1[2]), fexp2(EB1[3]));

        // energy for tile t+1 (A-frags prefetched one iteration ago)
        if (t + 1 < NT) {
            EA0 = __builtin_amdgcn_mfma_f32_16x16x32_bf16(aN0, bqA, z, 0, 0, 0);
            EA1 = __builtin_amdgcn_mfma_f32_16x16x32_bf16(aN1, bqA, z, 0, 0, 0);
            EB0 = __builtin_amdgcn_mfma_f32_16x16x32_bf16(aN0, bqB, z, 0, 0, 0);
            EB1 = __builtin_amdgcn_mfma_f32_16x16x32_bf16(aN1, bqB, z, 0, 0, 0);
        }
        bf16x8 cifU = cifC;
        {
            // always issue (clamped at tail) to keep per-iter VMEM count uniform
            int nw2 = (t + 2 < NT) ? (nbase + (t + 2) * 128 + q4 * 32) : (nbase + q4 * 32);
            aN0 = Qv[(size_t)(nw2 + c16) * 4 + g];
            aN1 = Qv[(size_t)(nw2 + 16 + c16) * 4 + g];
            cifC = cifN;
            cifN = ld_av(irow + nw2 + 4 * g);
        }

        __builtin_amdgcn_s_setprio(1);
        acsA = __builtin_amdgcn_mfma_f32_16x16x32_bf16(cifU, bpA, acsA, 0, 0, 0);
        acsB = __builtin_amdgcn_mfma_f32_16x16x32_bf16(cifU, bpB, acsB, 0, 0, 0);
#pragma unroll
        for (int ci = 0; ci < 4; ++ci) {
            const char* rp = buf + (16 * ci + c16) * 256;
            bf16x4 lo = *(const bf16x4*)(rp + lo_off);
            bf16x4 hi = *(const bf16x4*)(rp + hi_off);
            bf16x8 xv;
            xv[0]=lo[0];xv[1]=lo[1];xv[2]=lo[2];xv[3]=lo[3];
            xv[4]=hi[0];xv[5]=hi[1];xv[6]=hi[2];xv[7]=hi[3];
            acc[ci][0] = __builtin_amdgcn_mfma_f32_16x16x32_bf16(xv, bpA, acc[ci][0], 0, 0, 0);
            acc[ci][1] = __builtin_amdgcn_mfma_f32_16x16x32_bf16(xv, bpB, acc[ci][1], 0, 0, 0);
        }
        __builtin_amdgcn_s_setprio(0);

        // counted barrier: only the 2 gload_lds (oldest) must have landed;
        // the 4 newer prefetch loads stay in flight across the barrier.
        asm volatile("s_waitcnt vmcnt(4)" ::: "memory");
        __builtin_amdgcn_s_barrier();
    }

    // ---- epilogue ----
    __syncthreads();   // full drain before reusing lds as epi scratch
    if (l < 16) {
        csL[q4 * 64 + 16 * (2 * jh + 0) + l] = acsA[0];
        csL[q4 * 64 + 16 * (2 * jh + 1) + l] = acsB[0];
    }
    bf16_t* epi = (bf16_t*)lds;   // [4 nsplit][64 cc][72 mm] bf16
#pragma unroll
    for (int ci = 0; ci < 4; ++ci)
#pragma unroll
        for (int jj = 0; jj < 2; ++jj)
#pragma unroll
            for (int r = 0; r < 4; ++r) {
                int cc = 16 * ci + 4 * g + r;
                int mm = jh * 32 + jj * 16 + c16;
                epi[((size_t)q4 * 64 + cc) * 72 + mm] = (bf16_t)acc[ci][jj][r];
            }
    __syncthreads();
    {
        int c = tid >> 3, m8 = (tid & 7) * 8;
        float s[8] = {0.f,0.f,0.f,0.f,0.f,0.f,0.f,0.f};
#pragma unroll
        for (int q = 0; q < 4; ++q) {
            bf16x8 v = *(const bf16x8*)&epi[((size_t)q * 64 + c) * 72 + m8];
#pragma unroll
            for (int i = 0; i < 8; ++i) s[i] += (float)v[i];
        }
        bf16x8 o;
#pragma unroll
        for (int i = 0; i < 8; ++i) o[i] = (bf16_t)s[i];
        *(bf16x8*)&part[(((size_t)chunk * BB + b) * CP + c) * NN + m0 + m8] = o;
    }
    if (tid < 64) {
        float cp = csL[tid] + csL[64 + tid] + csL[128 + tid] + csL[192 + tid];
        cpart[((size_t)chunk * BB + b) * NN + m0 + tid] = cp;
    }
}

// K4: tile kernel: combine partials + L1 renorm + T in LDS + t-conv (f32 VALU) + Y. No atomics.
__global__ __launch_bounds__(256) void k_post(
    const bf16_t* __restrict__ part, const float* __restrict__ cpart,
    const float* __restrict__ pfeat, const float* __restrict__ tw,
    const float* __restrict__ tb, float* __restrict__ Y)
{
    __shared__ float Tl[64][66];    // [c][n]
    __shared__ float twt[64][68];   // [c][o], 16B-aligned rows (272B)
    int tid = threadIdx.x;
    int b = blockIdx.y;
    int n0 = blockIdx.x * 64;
    int nl = tid & 63;
    int grp = tid >> 6;             // 0..3

    // stage tw transposed: twt[c][o]
    for (int i = tid; i < 64 * 64; i += 256)
        twt[i & 63][i >> 6] = tw[i];

    // phase 1: T = pfeat - (sum part) * ic   (fully coalesced, c-major streams)
    float cs = 0.f;
#pragma unroll
    for (int sp = 0; sp < SPLITN; ++sp)
        cs += cpart[((size_t)sp * BB + b) * NN + n0 + nl];
    float ic = 1.f / (1e-9f + cs);
#pragma unroll
    for (int k = 0; k < 16; ++k) {
        int c = k * 4 + grp;
        float xr = 0.f;
#pragma unroll
        for (int sp = 0; sp < SPLITN; ++sp)
            xr += (float)part[(((size_t)sp * BB + b) * CP + c) * NN + n0 + nl];
        Tl[c][nl] = pfeat[((size_t)b * CP + c) * NN + n0 + nl] - xr * ic;
    }
    __syncthreads();

    // phase 2: thread (nl, grp) -> o in [grp*16, grp*16+16)
    float y0 = tb[grp * 16 + 0], y1 = tb[grp * 16 + 1], y2 = tb[grp * 16 + 2], y3 = tb[grp * 16 + 3];
    float y4 = tb[grp * 16 + 4], y5 = tb[grp * 16 + 5], y6 = tb[grp * 16 + 6], y7 = tb[grp * 16 + 7];
    float y8 = tb[grp * 16 + 8], y9 = tb[grp * 16 + 9], yA = tb[grp * 16 +10], yB = tb[grp * 16 +11];
    float yC = tb[grp * 16 +12], yD = tb[grp * 16 +13], yE = tb[grp * 16 +14], yF = tb[grp * 16 +15];
#pragma unroll 4
    for (int c = 0; c < 64; ++c) {
        float t = Tl[c][nl];
        const float4* wr = (const float4*)&twt[c][grp * 16];
        float4 w0 = wr[0], w1 = wr[1], w2 = wr[2], w3 = wr[3];
        y0 += w0.x * t; y1 += w0.y * t; y2 += w0.z * t; y3 += w0.w * t;
        y4 += w1.x * t; y5 += w1.y * t; y6 += w1.z * t; y7 += w1.w * t;
        y8 += w2.x * t; y9 += w2.y * t; yA += w2.z * t; yB += w2.w * t;
        yC += w3.x * t; yD += w3.y * t; yE += w3.z * t; yF += w3.w * t;
    }
    float* yb = Y + ((size_t)b * CP + grp * 16) * NN + n0 + nl;
    yb[0 * NN] = y0;  yb[1 * NN] = y1;  yb[2 * NN] = y2;  yb[3 * NN] = y3;
    yb[4 * NN] = y4;  yb[5 * NN] = y5;  yb[6 * NN] = y6;  yb[7 * NN] = y7;
    yb[8 * NN] = y8;  yb[9 * NN] = y9;  yb[10 * NN] = yA; yb[11 * NN] = yB;
    yb[12 * NN] = yC; yb[13 * NN] = yD; yb[14 * NN] = yE; yb[15 * NN] = yF;
}

// K4b: BN stats from Y: block = (n-chunk 2048, o, b); wave reduce + few atomics
__global__ __launch_bounds__(256) void k_bnstat(
    const float* __restrict__ Y, float* __restrict__ bnred)
{
    __shared__ float red[8];
    int tid = threadIdx.x;
    int o = blockIdx.y, b = blockIdx.z;
    const float* row = Y + ((size_t)b * CP + o) * NN + blockIdx.x * 2048 + tid * 8;
    float4 a = *(const float4*)row;
    float4 c4 = *(const float4*)(row + 4);
    float sv = ((a.x + a.y) + (a.z + a.w)) + ((c4.x + c4.y) + (c4.z + c4.w));
    float sq = ((a.x*a.x + a.y*a.y) + (a.z*a.z + a.w*a.w))
             + ((c4.x*c4.x + c4.y*c4.y) + (c4.z*c4.z + c4.w*c4.w));
#pragma unroll
    for (int off = 1; off < 64; off <<= 1) {
        sv += __shfl_xor(sv, off);
        sq += __shfl_xor(sq, off);
    }
    int wv = tid >> 6;
    if ((tid & 63) == 0) { red[wv] = sv; red[4 + wv] = sq; }
    __syncthreads();
    if (tid == 0) {
        atomicAdd(&bnred[o], red[0] + red[1] + red[2] + red[3]);
        atomicAdd(&bnred[64 + o], red[4] + red[5] + red[6] + red[7]);
    }
}

// K5: BN finalize + ReLU + residual (float4 vectorized)
__global__ __launch_bounds__(256) void k_final(
    const float* __restrict__ Y, const float* __restrict__ pfeat,
    const float* __restrict__ gamma, const float* __restrict__ beta,
    const float* __restrict__ bnred, float* __restrict__ out)
{
    int idx4 = blockIdx.x * 256 + threadIdx.x;   // flat over [B][CP][NN]/4
    int o = ((idx4 * 4) / NN) & (CP - 1);
    const float invcnt = 1.f / (float)(BB * NN);
    float mean = bnred[o] * invcnt;
    float var = bnred[64 + o] * invcnt - mean * mean;
    float sc = gamma[o] * rsqrtf(var + 1e-5f);
    float sh = beta[o] - mean * sc;
    float4 y = ((const float4*)Y)[idx4];
    float4 p = ((const float4*)pfeat)[idx4];
    float4 r;
    r.x = p.x + fmaxf(y.x * sc + sh, 0.f);
    r.y = p.y + fmaxf(y.y * sc + sh, 0.f);
    r.z = p.z + fmaxf(y.z * sc + sh, 0.f);
    r.w = p.w + fmaxf(y.w * sc + sh, 0.f);
    ((float4*)out)[idx4] = r;
}

extern "C" void kernel_launch(void* const* d_in, const int* in_sizes, int n_in,
                              void* d_out, int out_size, void* d_ws, size_t ws_size,
                              hipStream_t stream) {
    const float* pts_img = (const float*)d_in[0];
    const float* img     = (const float*)d_in[1];
    const float* pfeat   = (const float*)d_in[2];
    const float* qkw     = (const float*)d_in[3];
    const float* vw      = (const float*)d_in[4];
    const float* vb      = (const float*)d_in[5];
    const float* tw      = (const float*)d_in[6];
    const float* tb      = (const float*)d_in[7];
    const float* gamma   = (const float*)d_in[8];
    const float* beta    = (const float*)d_in[9];

    // workspace layout (bytes), total ~35.3 MB
    char* base = (char*)d_ws;
    bf16_t* Qb      = (bf16_t*)(base);                  // 1,048,576   [B][N][32]
    bf16_t* XVb     = (bf16_t*)(base + 1048576);        // 2,097,152   [B][64][N]
    bf16_t* XVs     = (bf16_t*)(base + 3145728);        // 2,097,152   [B][64][N] irs-scaled, pre-swizzled
    float*  rowsumG = (float*)(base + 5251072);         // 65,536      [B][N]
    float*  bn      = (float*)(base + 5316608);         // 512
    bf16_t* irsb    = (bf16_t*)(base + 5317120);        // 32,768      [B][N] bf16
    float*  cpart   = (float*)(base + 5349888);         // 131,072     [SPLITN][B][N]
    float*  Y       = (float*)(base + 5874176);         // 4,194,304   [B][64][N]
    bf16_t* part    = (bf16_t*)(base + 10068480);       // 4,194,304   [SPLITN][B][64][N] bf16
    float*  imgT    = (float*)(base + 26845696);        // 8,388,608   [B][HW][64]

    hipMemsetAsync(base + 5251072, 0, 66048, stream);  // rowsumG + bn (contiguous)
    k_timg<<<dim3((HH * WW) / 64, BB), 256, 0, stream>>>(img, imgT);
    k_fuse<<<(BB * NN) / 16, 256, 0, stream>>>(pts_img, imgT, pfeat, qkw, vw, vb, Qb, XVb);
    k_rowsum<<<dim3(NN / 64, SPLITM, BB), 256, 0, stream>>>(Qb, rowsumG);
    k_scale<<<dim3(NN / 1024, BB, 4), 256, 0, stream>>>(rowsumG, XVb, XVs, irsb);
    k_attn<<<dim3(NN / 64, SPLITN, BB), 512, 0, stream>>>(Qb, XVs, irsb, part, cpart);
    k_post<<<dim3(NN / 64, BB), 256, 0, stream>>>(part, cpart, pfeat, tw, tb, Y);
    k_bnstat<<<dim3(NN / 2048, CP, BB), 256, 0, stream>>>(Y, bn);
    k_final<<<(BB * CP * NN) / 1024, 256, 0, stream>>>(Y, pfeat, gamma, beta, bn, (float*)d_out);
}

// Round 15
// 104.973 us; speedup vs baseline: 2.0047x; 1.0793x over previous
//
#include <hip/hip_runtime.h>
#include <math.h>

#define BB 2
#define NN 8192
#define CI 64
#define CP 64
#define HH 128
#define WW 128
#define DD 32
#define CF 128
#define SPLITM 8
#define SPLITN 2

typedef __bf16 bf16_t;
typedef __bf16 bf16x8 __attribute__((ext_vector_type(8)));
typedef __bf16 bf16x4 __attribute__((ext_vector_type(4)));
typedef float f32x4 __attribute__((ext_vector_type(4)));

#define SQ_L2E 1.2011224087864498f   /* sqrt(log2(e)) */

__device__ __forceinline__ float fexp2(float x) { return __builtin_amdgcn_exp2f(x); }

__device__ __forceinline__ bf16x8 pack8(float a0,float a1,float a2,float a3,
                                        float b0,float b1,float b2,float b3){
    bf16x8 r;
    r[0]=(bf16_t)a0; r[1]=(bf16_t)a1; r[2]=(bf16_t)a2; r[3]=(bf16_t)a3;
    r[4]=(bf16_t)b0; r[5]=(bf16_t)b1; r[6]=(bf16_t)b2; r[7]=(bf16_t)b3;
    return r;
}

__device__ __forceinline__ bf16x8 ld_av(const bf16_t* p){
    bf16x4 lo = *(const bf16x4*)p;
    bf16x4 hi = *(const bf16x4*)(p + 16);
    bf16x8 r;
    r[0]=lo[0];r[1]=lo[1];r[2]=lo[2];r[3]=lo[3];
    r[4]=hi[0];r[5]=hi[1];r[6]=hi[2];r[7]=hi[3];
    return r;
}

__device__ __forceinline__ void gload_lds16(const void* g, void* l) {
    __builtin_amdgcn_global_load_lds(
        (const __attribute__((address_space(1))) unsigned int*)g,
        (__attribute__((address_space(3))) unsigned int*)l, 16, 0, 0);
}

// transpose img [B][64][HW] -> imgT [B][HW][64]
__global__ __launch_bounds__(256) void k_timg(const float* __restrict__ img, float* __restrict__ imgT) {
    __shared__ float tile[64][65];
    int b = blockIdx.y;
    int pos0 = blockIdx.x * 64;
    int tid = threadIdx.x;
    int q = tid >> 6, r = tid & 63;
    const float* src = img + (size_t)b * CI * (HH * WW);
#pragma unroll
    for (int cc = 0; cc < 16; ++cc) {
        int c = cc * 4 + q;
        tile[c][r] = src[(size_t)c * (HH * WW) + pos0 + r];
    }
    __syncthreads();
    float* dst = imgT + ((size_t)b * (HH * WW) + pos0) * 64;
#pragma unroll
    for (int pp = 0; pp < 16; ++pp) {
        int pos = pp * 4 + q;
        dst[(size_t)pos * 64 + r] = tile[r][pos];
    }
}

// K1: bilinear gather (fp32) -> fus bf16 in LDS -> Q/V projections via MFMA
// (weights as register A-frags loaded once from global; B-frags from fus LDS).
__global__ __launch_bounds__(256) void k_fuse(
    const float* __restrict__ pts_img, const float* __restrict__ imgT,
    const float* __restrict__ pfeat, const float* __restrict__ qkw,
    const float* __restrict__ vw, const float* __restrict__ vb,
    bf16_t* __restrict__ Qb, bf16_t* __restrict__ XVb)
{
    __shared__ __align__(16) bf16_t fusb[16][136];   // 272B row stride -> 2-way max (free)
    int tid = threadIdx.x;
    int w = tid >> 6, l = tid & 63;
    int p0 = blockIdx.x * 16;
    int bb = p0 / NN, n0 = p0 % NN;

#pragma unroll
    for (int i = 0; i < 4; ++i) {
        int pt = i * 4 + w;
        int n = n0 + pt;
        float x = pts_img[(size_t)(p0 + pt) * 2 + 0];
        float y = pts_img[(size_t)(p0 + pt) * 2 + 1];
        float ix = (x + 1.f) * 0.5f * WW - 0.5f;
        float iy = (y + 1.f) * 0.5f * HH - 0.5f;
        float x0 = floorf(ix), y0 = floorf(iy);
        float wx1 = ix - x0, wx0 = 1.f - wx1;
        float wy1 = iy - y0, wy0 = 1.f - wy1;
        int xi0 = (int)x0, yi0 = (int)y0;
        const float* base = imgT + (size_t)bb * (HH * WW) * 64 + l;
        float iv = 0.f;
#pragma unroll
        for (int cr = 0; cr < 4; ++cr) {
            int xi = xi0 + (cr & 1), yi = yi0 + (cr >> 1);
            float wgt = ((cr & 1) ? wx1 : wx0) * ((cr >> 1) ? wy1 : wy0);
            bool v = (xi >= 0) & (xi <= WW - 1) & (yi >= 0) & (yi <= HH - 1);
            int cx = min(max(xi, 0), WW - 1), cy = min(max(yi, 0), HH - 1);
            float s = base[((size_t)cy * WW + cx) * 64];
            iv += (v ? s : 0.f) * wgt;
        }
        float pv = pfeat[((size_t)bb * CP + l) * NN + n];
        fusb[pt][l] = (bf16_t)iv;
        fusb[pt][64 + l] = (bf16_t)pv;
    }
    __syncthreads();

    int g = l >> 4, c16 = l & 15;
    f32x4 z = {0.f, 0.f, 0.f, 0.f};
    if (w < 2) {
        // Q projection: o in [w*16, w*16+16), k over 128
        const float* wr = qkw + (size_t)(w * 16 + c16) * 128;
        f32x4 acc = z;
#pragma unroll
        for (int kk = 0; kk < 4; ++kk) {
            float4 a0 = *(const float4*)&wr[kk * 32 + 4 * g];
            float4 a1 = *(const float4*)&wr[kk * 32 + 16 + 4 * g];
            bf16x8 af = pack8(a0.x, a0.y, a0.z, a0.w, a1.x, a1.y, a1.z, a1.w);
            bf16x8 bfr = ld_av(&fusb[c16][kk * 32 + 4 * g]);
            acc = __builtin_amdgcn_mfma_f32_16x16x32_bf16(af, bfr, acc, 0, 0, 0);
        }
        bf16x4 qo;
#pragma unroll
        for (int r = 0; r < 4; ++r) qo[r] = (bf16_t)(acc[r] * SQ_L2E);
        *(bf16x4*)&Qb[((size_t)bb * NN + n0 + c16) * DD + w * 16 + 4 * g] = qo;
    } else {
        // V projection: o in [vh*32, vh*32+32), k over 64 (pfeat half of fus)
        int vh = w - 2;
        const float* wrA = vw + (size_t)(vh * 32 + c16) * 64;
        const float* wrB = vw + (size_t)(vh * 32 + 16 + c16) * 64;
        f32x4 accA = z, accB = z;
#pragma unroll
        for (int kk = 0; kk < 2; ++kk) {
            bf16x8 bfr = ld_av(&fusb[c16][64 + kk * 32 + 4 * g]);
            float4 a0 = *(const float4*)&wrA[kk * 32 + 4 * g];
            float4 a1 = *(const float4*)&wrA[kk * 32 + 16 + 4 * g];
            accA = __builtin_amdgcn_mfma_f32_16x16x32_bf16(
                pack8(a0.x, a0.y, a0.z, a0.w, a1.x, a1.y, a1.z, a1.w), bfr, accA, 0, 0, 0);
            a0 = *(const float4*)&wrB[kk * 32 + 4 * g];
            a1 = *(const float4*)&wrB[kk * 32 + 16 + 4 * g];
            accB = __builtin_amdgcn_mfma_f32_16x16x32_bf16(
                pack8(a0.x, a0.y, a0.z, a0.w, a1.x, a1.y, a1.z, a1.w), bfr, accB, 0, 0, 0);
        }
#pragma unroll
        for (int r = 0; r < 4; ++r) {
            int oA = vh * 32 + 4 * g + r;
            int oB = oA + 16;
            XVb[((size_t)bb * CP + oA) * NN + n0 + c16] = (bf16_t)(accA[r] + vb[oA]);
            XVb[((size_t)bb * CP + oB) * NN + n0 + c16] = (bf16_t)(accB[r] + vb[oB]);
        }
    }
}

// K2: rowsum[n] = sum_m exp2(E[n,m]) (no max; exp2 headroom). m-split + atomics.
__global__ __launch_bounds__(256) void k_rowsum(
    const bf16_t* __restrict__ Qb, float* __restrict__ rowsumG)
{
    int b = blockIdx.z;
    int n0 = blockIdx.x * 64;
    int mchunk = blockIdx.y * (NN / SPLITM);
    int tid = threadIdx.x;
    int wv = tid >> 6, l = tid & 63;
    int g = l >> 4, c16 = l & 15;
    const bf16x8* Qv = (const bf16x8*)(Qb + (size_t)b * NN * DD);
    f32x4 z = {0.f, 0.f, 0.f, 0.f};

    bf16x8 A0 = Qv[(size_t)(n0 +  0 + c16) * 4 + g];
    bf16x8 A1 = Qv[(size_t)(n0 + 16 + c16) * 4 + g];
    bf16x8 A2 = Qv[(size_t)(n0 + 32 + c16) * 4 + g];
    bf16x8 A3 = Qv[(size_t)(n0 + 48 + c16) * 4 + g];

    float rs[4][4];
#pragma unroll
    for (int a = 0; a < 4; ++a)
#pragma unroll
        for (int r = 0; r < 4; ++r) rs[a][r] = 0.f;

    int mbase = mchunk + wv * 64;
    bf16x8 Bn0 = Qv[(size_t)(mbase +  0 + c16) * 4 + g];
    bf16x8 Bn1 = Qv[(size_t)(mbase + 16 + c16) * 4 + g];
    bf16x8 Bn2 = Qv[(size_t)(mbase + 32 + c16) * 4 + g];
    bf16x8 Bn3 = Qv[(size_t)(mbase + 48 + c16) * 4 + g];

    const int NIT = NN / SPLITM / 256;  // 4
    for (int it = 0; it < NIT; ++it) {
        bf16x8 B0 = Bn0, B1 = Bn1, B2 = Bn2, B3 = Bn3;
        int mnext = mbase + 256;
        if (it + 1 < NIT) {
            Bn0 = Qv[(size_t)(mnext +  0 + c16) * 4 + g];
            Bn1 = Qv[(size_t)(mnext + 16 + c16) * 4 + g];
            Bn2 = Qv[(size_t)(mnext + 32 + c16) * 4 + g];
            Bn3 = Qv[(size_t)(mnext + 48 + c16) * 4 + g];
        }
#define ROWSTEP(Aa, a)                                                        \
        {                                                                     \
            f32x4 e0 = __builtin_amdgcn_mfma_f32_16x16x32_bf16(Aa, B0, z, 0, 0, 0); \
            f32x4 e1 = __builtin_amdgcn_mfma_f32_16x16x32_bf16(Aa, B1, z, 0, 0, 0); \
            f32x4 e2 = __builtin_amdgcn_mfma_f32_16x16x32_bf16(Aa, B2, z, 0, 0, 0); \
            f32x4 e3 = __builtin_amdgcn_mfma_f32_16x16x32_bf16(Aa, B3, z, 0, 0, 0); \
            _Pragma("unroll")                                                 \
            for (int r = 0; r < 4; ++r)                                       \
                rs[a][r] += (fexp2(e0[r]) + fexp2(e1[r])) + (fexp2(e2[r]) + fexp2(e3[r])); \
        }
        ROWSTEP(A0, 0) ROWSTEP(A1, 1) ROWSTEP(A2, 2) ROWSTEP(A3, 3)
#undef ROWSTEP
        mbase = mnext;
    }
#pragma unroll
    for (int a = 0; a < 4; ++a)
#pragma unroll
        for (int r = 0; r < 4; ++r) {
            float v = rs[a][r];
            v += __shfl_xor(v, 1);
            v += __shfl_xor(v, 2);
            v += __shfl_xor(v, 4);
            v += __shfl_xor(v, 8);
            if (c16 == 0)
                atomicAdd(&rowsumG[(size_t)b * NN + n0 + 16 * a + 4 * g + r], v);
        }
}

// K2b: XVs = XV * irs[n] written PRE-SWIZZLED (byte-in-256-chunk ^= (c&7)<<4); irsb = bf16 1/rowsum
__global__ __launch_bounds__(256) void k_scale(
    const float* __restrict__ rowsumG, const bf16_t* __restrict__ XVb,
    bf16_t* __restrict__ XVs, bf16_t* __restrict__ irsb)
{
    int b = blockIdx.y;
    int cq = blockIdx.z;             // c-quarter
    int n = (blockIdx.x * 256 + threadIdx.x) * 4;
    float4 rs = *(const float4*)&rowsumG[(size_t)b * NN + n];
    float ir0 = 1.f / rs.x, ir1 = 1.f / rs.y, ir2 = 1.f / rs.z, ir3 = 1.f / rs.w;
    if (cq == 0) {
        bf16x4 iv;
        iv[0] = (bf16_t)ir0; iv[1] = (bf16_t)ir1; iv[2] = (bf16_t)ir2; iv[3] = (bf16_t)ir3;
        *(bf16x4*)&irsb[(size_t)b * NN + n] = iv;
    }
    const bf16_t* src = XVb + ((size_t)b * CP + cq * 16) * NN + n;
    char* dstbase = (char*)(XVs + ((size_t)b * CP + cq * 16) * NN);
    size_t nb = (size_t)n * 2;
    size_t hi = nb & ~(size_t)255;
    size_t lo = nb & 255;
#pragma unroll
    for (int c = 0; c < 16; ++c) {
        bf16x4 v = *(const bf16x4*)&src[(size_t)c * NN];
        bf16x4 o;
        o[0] = (bf16_t)((float)v[0] * ir0);
        o[1] = (bf16_t)((float)v[1] * ir1);
        o[2] = (bf16_t)((float)v[2] * ir2);
        o[3] = (bf16_t)((float)v[3] * ir3);
        size_t sb = hi | (lo ^ ((size_t)(c & 7) << 4));
        *(bf16x4*)(dstbase + (size_t)c * NN * 2 + sb) = o;
    }
}

// stage one 128-n XVs tile (64 rows x 256B, pre-swizzled source, linear dest) into LDS
__device__ __forceinline__ void stage_tile(const char* xvbase, int n0, char* ldsbuf, int wv, int l) {
#pragma unroll
    for (int k = 0; k < 2; ++k) {
        int R0 = k * 32 + wv * 4;          // 8 waves x 2 calls = rows 0..63
        int row = R0 + (l >> 4);
        const char* g = xvbase + (size_t)row * (NN * 2) + (size_t)n0 * 2 + (size_t)(l & 15) * 16;
        gload_lds16(g, ldsbuf + R0 * 256);
    }
}

// K3: LDS-staged main loop, 2-deep energy pipeline + counted-vmcnt barrier (T4).
__global__ __launch_bounds__(512, 4) void k_attn(
    const bf16_t* __restrict__ Qb, const bf16_t* __restrict__ XVs,
    const bf16_t* __restrict__ irsb,
    bf16_t* __restrict__ part, float* __restrict__ cpart)
{
    __shared__ __align__(16) char lds[4 * 64 * 72 * 2];  // 36864B
    __shared__ float csL[4 * 64];

    int b = blockIdx.z;
    int m0 = blockIdx.x * 64;
    int chunk = blockIdx.y;
    int tid = threadIdx.x;
    int wv = tid >> 6, l = tid & 63;
    int g = l >> 4, c16 = l & 15;
    int q4 = wv & 3;        // n-split
    int jh = wv >> 2;       // m-half

    const bf16x8* Qv = (const bf16x8*)(Qb + (size_t)b * NN * DD);
    const char* xvbase = (const char*)(XVs + (size_t)b * CP * NN);
    const bf16_t* irow = irsb + (size_t)b * NN;

    bf16x8 bqA = Qv[(size_t)(m0 + jh * 32 + c16) * 4 + g];
    bf16x8 bqB = Qv[(size_t)(m0 + jh * 32 + 16 + c16) * 4 + g];

    f32x4 z = {0.f, 0.f, 0.f, 0.f};
    f32x4 acc[4][2];
    f32x4 acsA = z, acsB = z;
#pragma unroll
    for (int ci = 0; ci < 4; ++ci) { acc[ci][0] = z; acc[ci][1] = z; }

    const int NT = (NN / SPLITN) / 128;   // 32 tiles
    int nbase = chunk * (NN / SPLITN);

    stage_tile(xvbase, nbase, lds, wv, l);
    int nw0 = nbase + q4 * 32;
    bf16x8 aN0 = Qv[(size_t)(nw0 + c16) * 4 + g];
    bf16x8 aN1 = Qv[(size_t)(nw0 + 16 + c16) * 4 + g];
    bf16x8 cifC = ld_av(irow + nw0 + 4 * g);

    f32x4 EA0 = __builtin_amdgcn_mfma_f32_16x16x32_bf16(aN0, bqA, z, 0, 0, 0);
    f32x4 EA1 = __builtin_amdgcn_mfma_f32_16x16x32_bf16(aN1, bqA, z, 0, 0, 0);
    f32x4 EB0 = __builtin_amdgcn_mfma_f32_16x16x32_bf16(aN0, bqB, z, 0, 0, 0);
    f32x4 EB1 = __builtin_amdgcn_mfma_f32_16x16x32_bf16(aN1, bqB, z, 0, 0, 0);

    int nw1 = nbase + 128 + q4 * 32;
    aN0 = Qv[(size_t)(nw1 + c16) * 4 + g];
    aN1 = Qv[(size_t)(nw1 + 16 + c16) * 4 + g];
    bf16x8 cifN = ld_av(irow + nw1 + 4 * g);
    __syncthreads();

    const int swz = (c16 & 7) << 4;
    const int blo = (q4 * 32 + 4 * g) * 2;
    const int lo_off = blo ^ swz;
    const int hi_off = (blo + 32) ^ swz;

    for (int t = 0; t < NT; ++t) {
        char* buf = lds + (t & 1) * 16384;
        if (t + 1 < NT)
            stage_tile(xvbase, nbase + (t + 1) * 128, lds + ((t + 1) & 1) * 16384, wv, l);

        bf16x8 bpA = pack8(fexp2(EA0[0]), fexp2(EA0[1]), fexp2(EA0[2]), fexp2(EA0[3]),
                           fexp2(EA1[0]), fexp2(EA1[1]), fexp2(EA1[2]), fexp2(EA1[3]));
        bf16x8 bpB = pack8(fexp2(EB0[0]), fexp2(EB0[1]), fexp2(EB0[2]), fexp2(EB0[3]),
                           fexp2(EB1[0]), fexp2(EB1[1]), fexp2(EB1[2]), fexp2(EB1[3]));

        if (t + 1 < NT) {
            EA0 = __builtin_amdgcn_mfma_f32_16x16x32_bf16(aN0, bqA, z, 0, 0, 0);
            EA1 = __builtin_amdgcn_mfma_f32_16x16x32_bf16(aN1, bqA, z, 0, 0, 0);
            EB0 = __builtin_amdgcn_mfma_f32_16x16x32_bf16(aN0, bqB, z, 0, 0, 0);
            EB1 = __builtin_amdgcn_mfma_f32_16x16x32_bf16(aN1, bqB, z, 0, 0, 0);
        }
        bf16x8 cifU = cifC;
        {
            int nw2 = (t + 2 < NT) ? (nbase + (t + 2) * 128 + q4 * 32) : (nbase + q4 * 32);
            aN0 = Qv[(size_t)(nw2 + c16) * 4 + g];
            aN1 = Qv[(size_t)(nw2 + 16 + c16) * 4 + g];
            cifC = cifN;
            cifN = ld_av(irow + nw2 + 4 * g);
        }

        __builtin_amdgcn_s_setprio(1);
        acsA = __builtin_amdgcn_mfma_f32_16x16x32_bf16(cifU, bpA, acsA, 0, 0, 0);
        acsB = __builtin_amdgcn_mfma_f32_16x16x32_bf16(cifU, bpB, acsB, 0, 0, 0);
#pragma unroll
        for (int ci = 0; ci < 4; ++ci) {
            const char* rp = buf + (16 * ci + c16) * 256;
            bf16x4 lo = *(const bf16x4*)(rp + lo_off);
            bf16x4 hi = *(const bf16x4*)(rp + hi_off);
            bf16x8 xv;
            xv[0]=lo[0];xv[1]=lo[1];xv[2]=lo[2];xv[3]=lo[3];
            xv[4]=hi[0];xv[5]=hi[1];xv[6]=hi[2];xv[7]=hi[3];
            acc[ci][0] = __builtin_amdgcn_mfma_f32_16x16x32_bf16(xv, bpA, acc[ci][0], 0, 0, 0);
            acc[ci][1] = __builtin_amdgcn_mfma_f32_16x16x32_bf16(xv, bpB, acc[ci][1], 0, 0, 0);
        }
        __builtin_amdgcn_s_setprio(0);

        asm volatile("s_waitcnt vmcnt(4)" ::: "memory");
        __builtin_amdgcn_s_barrier();
    }

    // ---- epilogue ----
    __syncthreads();
    if (l < 16) {
        csL[q4 * 64 + 16 * (2 * jh + 0) + l] = acsA[0];
        csL[q4 * 64 + 16 * (2 * jh + 1) + l] = acsB[0];
    }
    bf16_t* epi = (bf16_t*)lds;   // [4 nsplit][64 cc][72 mm] bf16
#pragma unroll
    for (int ci = 0; ci < 4; ++ci)
#pragma unroll
        for (int jj = 0; jj < 2; ++jj)
#pragma unroll
            for (int r = 0; r < 4; ++r) {
                int cc = 16 * ci + 4 * g + r;
                int mm = jh * 32 + jj * 16 + c16;
                epi[((size_t)q4 * 64 + cc) * 72 + mm] = (bf16_t)acc[ci][jj][r];
            }
    __syncthreads();
    {
        int c = tid >> 3, m8 = (tid & 7) * 8;
        float s[8] = {0.f,0.f,0.f,0.f,0.f,0.f,0.f,0.f};
#pragma unroll
        for (int q = 0; q < 4; ++q) {
            bf16x8 v = *(const bf16x8*)&epi[((size_t)q * 64 + c) * 72 + m8];
#pragma unroll
            for (int i = 0; i < 8; ++i) s[i] += (float)v[i];
        }
        bf16x8 o;
#pragma unroll
        for (int i = 0; i < 8; ++i) o[i] = (bf16_t)s[i];
        *(bf16x8*)&part[(((size_t)chunk * BB + b) * CP + c) * NN + m0 + m8] = o;
    }
    if (tid < 64) {
        float cp = csL[tid] + csL[64 + tid] + csL[128 + tid] + csL[192 + tid];
        cpart[((size_t)chunk * BB + b) * NN + m0 + tid] = cp;
    }
}

// K4: tile kernel: combine partials + L1 renorm + T in LDS + t-conv (f32 VALU) + Y. No atomics.
__global__ __launch_bounds__(256) void k_post(
    const bf16_t* __restrict__ part, const float* __restrict__ cpart,
    const float* __restrict__ pfeat, const float* __restrict__ tw,
    const float* __restrict__ tb, float* __restrict__ Y)
{
    __shared__ float Tl[64][66];    // [c][n]
    __shared__ float twt[64][68];   // [c][o], 16B-aligned rows (272B)
    int tid = threadIdx.x;
    int b = blockIdx.y;
    int n0 = blockIdx.x * 64;
    int nl = tid & 63;
    int grp = tid >> 6;             // 0..3

    for (int i = tid; i < 64 * 64; i += 256)
        twt[i & 63][i >> 6] = tw[i];

    float cs = 0.f;
#pragma unroll
    for (int sp = 0; sp < SPLITN; ++sp)
        cs += cpart[((size_t)sp * BB + b) * NN + n0 + nl];
    float ic = 1.f / (1e-9f + cs);
#pragma unroll
    for (int k = 0; k < 16; ++k) {
        int c = k * 4 + grp;
        float xr = 0.f;
#pragma unroll
        for (int sp = 0; sp < SPLITN; ++sp)
            xr += (float)part[(((size_t)sp * BB + b) * CP + c) * NN + n0 + nl];
        Tl[c][nl] = pfeat[((size_t)b * CP + c) * NN + n0 + nl] - xr * ic;
    }
    __syncthreads();

    float y0 = tb[grp * 16 + 0], y1 = tb[grp * 16 + 1], y2 = tb[grp * 16 + 2], y3 = tb[grp * 16 + 3];
    float y4 = tb[grp * 16 + 4], y5 = tb[grp * 16 + 5], y6 = tb[grp * 16 + 6], y7 = tb[grp * 16 + 7];
    float y8 = tb[grp * 16 + 8], y9 = tb[grp * 16 + 9], yA = tb[grp * 16 +10], yB = tb[grp * 16 +11];
    float yC = tb[grp * 16 +12], yD = tb[grp * 16 +13], yE = tb[grp * 16 +14], yF = tb[grp * 16 +15];
#pragma unroll 4
    for (int c = 0; c < 64; ++c) {
        float t = Tl[c][nl];
        const float4* wr = (const float4*)&twt[c][grp * 16];
        float4 w0 = wr[0], w1 = wr[1], w2 = wr[2], w3 = wr[3];
        y0 += w0.x * t; y1 += w0.y * t; y2 += w0.z * t; y3 += w0.w * t;
        y4 += w1.x * t; y5 += w1.y * t; y6 += w1.z * t; y7 += w1.w * t;
        y8 += w2.x * t; y9 += w2.y * t; yA += w2.z * t; yB += w2.w * t;
        yC += w3.x * t; yD += w3.y * t; yE += w3.z * t; yF += w3.w * t;
    }
    float* yb = Y + ((size_t)b * CP + grp * 16) * NN + n0 + nl;
    yb[0 * NN] = y0;  yb[1 * NN] = y1;  yb[2 * NN] = y2;  yb[3 * NN] = y3;
    yb[4 * NN] = y4;  yb[5 * NN] = y5;  yb[6 * NN] = y6;  yb[7 * NN] = y7;
    yb[8 * NN] = y8;  yb[9 * NN] = y9;  yb[10 * NN] = yA; yb[11 * NN] = yB;
    yb[12 * NN] = yC; yb[13 * NN] = yD; yb[14 * NN] = yE; yb[15 * NN] = yF;
}

// K4b: BN stats from Y: block = (n-chunk 2048, o, b); wave reduce + few atomics
__global__ __launch_bounds__(256) void k_bnstat(
    const float* __restrict__ Y, float* __restrict__ bnred)
{
    __shared__ float red[8];
    int tid = threadIdx.x;
    int o = blockIdx.y, b = blockIdx.z;
    const float* row = Y + ((size_t)b * CP + o) * NN + blockIdx.x * 2048 + tid * 8;
    float4 a = *(const float4*)row;
    float4 c4 = *(const float4*)(row + 4);
    float sv = ((a.x + a.y) + (a.z + a.w)) + ((c4.x + c4.y) + (c4.z + c4.w));
    float sq = ((a.x*a.x + a.y*a.y) + (a.z*a.z + a.w*a.w))
             + ((c4.x*c4.x + c4.y*c4.y) + (c4.z*c4.z + c4.w*c4.w));
#pragma unroll
    for (int off = 1; off < 64; off <<= 1) {
        sv += __shfl_xor(sv, off);
        sq += __shfl_xor(sq, off);
    }
    int wv = tid >> 6;
    if ((tid & 63) == 0) { red[wv] = sv; red[4 + wv] = sq; }
    __syncthreads();
    if (tid == 0) {
        atomicAdd(&bnred[o], red[0] + red[1] + red[2] + red[3]);
        atomicAdd(&bnred[64 + o], red[4] + red[5] + red[6] + red[7]);
    }
}

// K5: BN finalize + ReLU + residual (float4 vectorized)
__global__ __launch_bounds__(256) void k_final(
    const float* __restrict__ Y, const float* __restrict__ pfeat,
    const float* __restrict__ gamma, const float* __restrict__ beta,
    const float* __restrict__ bnred, float* __restrict__ out)
{
    int idx4 = blockIdx.x * 256 + threadIdx.x;   // flat over [B][CP][NN]/4
    int o = ((idx4 * 4) / NN) & (CP - 1);
    const float invcnt = 1.f / (float)(BB * NN);
    float mean = bnred[o] * invcnt;
    float var = bnred[64 + o] * invcnt - mean * mean;
    float sc = gamma[o] * rsqrtf(var + 1e-5f);
    float sh = beta[o] - mean * sc;
    float4 y = ((const float4*)Y)[idx4];
    float4 p = ((const float4*)pfeat)[idx4];
    float4 r;
    r.x = p.x + fmaxf(y.x * sc + sh, 0.f);
    r.y = p.y + fmaxf(y.y * sc + sh, 0.f);
    r.z = p.z + fmaxf(y.z * sc + sh, 0.f);
    r.w = p.w + fmaxf(y.w * sc + sh, 0.f);
    ((float4*)out)[idx4] = r;
}

extern "C" void kernel_launch(void* const* d_in, const int* in_sizes, int n_in,
                              void* d_out, int out_size, void* d_ws, size_t ws_size,
                              hipStream_t stream) {
    const float* pts_img = (const float*)d_in[0];
    const float* img     = (const float*)d_in[1];
    const float* pfeat   = (const float*)d_in[2];
    const float* qkw     = (const float*)d_in[3];
    const float* vw      = (const float*)d_in[4];
    const float* vb      = (const float*)d_in[5];
    const float* tw      = (const float*)d_in[6];
    const float* tb      = (const float*)d_in[7];
    const float* gamma   = (const float*)d_in[8];
    const float* beta    = (const float*)d_in[9];

    // workspace layout (bytes), total ~35.3 MB
    char* base = (char*)d_ws;
    bf16_t* Qb      = (bf16_t*)(base);                  // 1,048,576   [B][N][32]
    bf16_t* XVb     = (bf16_t*)(base + 1048576);        // 2,097,152   [B][64][N]
    bf16_t* XVs     = (bf16_t*)(base + 3145728);        // 2,097,152   [B][64][N] irs-scaled, pre-swizzled
    float*  rowsumG = (float*)(base + 5251072);         // 65,536      [B][N]
    float*  bn      = (float*)(base + 5316608);         // 512
    bf16_t* irsb    = (bf16_t*)(base + 5317120);        // 32,768      [B][N] bf16
    float*  cpart   = (float*)(base + 5349888);         // 131,072     [SPLITN][B][N]
    float*  Y       = (float*)(base + 5874176);         // 4,194,304   [B][64][N]
    bf16_t* part    = (bf16_t*)(base + 10068480);       // 4,194,304   [SPLITN][B][64][N] bf16
    float*  imgT    = (float*)(base + 26845696);        // 8,388,608   [B][HW][64]

    hipMemsetAsync(base + 5251072, 0, 66048, stream);  // rowsumG + bn (contiguous)
    k_timg<<<dim3((HH * WW) / 64, BB), 256, 0, stream>>>(img, imgT);
    k_fuse<<<(BB * NN) / 16, 256, 0, stream>>>(pts_img, imgT, pfeat, qkw, vw, vb, Qb, XVb);
    k_rowsum<<<dim3(NN / 64, SPLITM, BB), 256, 0, stream>>>(Qb, rowsumG);
    k_scale<<<dim3(NN / 1024, BB, 4), 256, 0, stream>>>(rowsumG, XVb, XVs, irsb);
    k_attn<<<dim3(NN / 64, SPLITN, BB), 512, 0, stream>>>(Qb, XVs, irsb, part, cpart);
    k_post<<<dim3(NN / 64, BB), 256, 0, stream>>>(part, cpart, pfeat, tw, tb, Y);
    k_bnstat<<<dim3(NN / 2048, CP, BB), 256, 0, stream>>>(Y, bn);
    k_final<<<(BB * CP * NN) / 1024, 256, 0, stream>>>(Y, pfeat, gamma, beta, bn, (float*)d_out);
}

// Round 16
// 102.942 us; speedup vs baseline: 2.0442x; 1.0197x over previous
//
#include <hip/hip_runtime.h>
#include <math.h>

#define BB 2
#define NN 8192
#define CI 64
#define CP 64
#define HH 128
#define WW 128
#define DD 32
#define CF 128
#define SPLITM 8
#define SPLITN 2

typedef __bf16 bf16_t;
typedef __bf16 bf16x8 __attribute__((ext_vector_type(8)));
typedef __bf16 bf16x4 __attribute__((ext_vector_type(4)));
typedef float f32x4 __attribute__((ext_vector_type(4)));

#define SQ_L2E 1.2011224087864498f   /* sqrt(log2(e)) */

__device__ __forceinline__ float fexp2(float x) { return __builtin_amdgcn_exp2f(x); }

__device__ __forceinline__ bf16x8 pack8(float a0,float a1,float a2,float a3,
                                        float b0,float b1,float b2,float b3){
    bf16x8 r;
    r[0]=(bf16_t)a0; r[1]=(bf16_t)a1; r[2]=(bf16_t)a2; r[3]=(bf16_t)a3;
    r[4]=(bf16_t)b0; r[5]=(bf16_t)b1; r[6]=(bf16_t)b2; r[7]=(bf16_t)b3;
    return r;
}

__device__ __forceinline__ bf16x8 ld_av(const bf16_t* p){
    bf16x4 lo = *(const bf16x4*)p;
    bf16x4 hi = *(const bf16x4*)(p + 16);
    bf16x8 r;
    r[0]=lo[0];r[1]=lo[1];r[2]=lo[2];r[3]=lo[3];
    r[4]=hi[0];r[5]=hi[1];r[6]=hi[2];r[7]=hi[3];
    return r;
}

__device__ __forceinline__ void gload_lds16(const void* g, void* l) {
    __builtin_amdgcn_global_load_lds(
        (const __attribute__((address_space(1))) unsigned int*)g,
        (__attribute__((address_space(3))) unsigned int*)l, 16, 0, 0);
}

// transpose img [B][64][HW] -> imgT [B][HW][64]
__global__ __launch_bounds__(256) void k_timg(const float* __restrict__ img, float* __restrict__ imgT) {
    __shared__ float tile[64][65];
    int b = blockIdx.y;
    int pos0 = blockIdx.x * 64;
    int tid = threadIdx.x;
    int q = tid >> 6, r = tid & 63;
    const float* src = img + (size_t)b * CI * (HH * WW);
#pragma unroll
    for (int cc = 0; cc < 16; ++cc) {
        int c = cc * 4 + q;
        tile[c][r] = src[(size_t)c * (HH * WW) + pos0 + r];
    }
    __syncthreads();
    float* dst = imgT + ((size_t)b * (HH * WW) + pos0) * 64;
#pragma unroll
    for (int pp = 0; pp < 16; ++pp) {
        int pos = pp * 4 + q;
        dst[(size_t)pos * 64 + r] = tile[r][pos];
    }
}

// K1: bilinear gather (fp32) -> fus bf16 in LDS -> Q/V projections via MFMA
__global__ __launch_bounds__(256) void k_fuse(
    const float* __restrict__ pts_img, const float* __restrict__ imgT,
    const float* __restrict__ pfeat, const float* __restrict__ qkw,
    const float* __restrict__ vw, const float* __restrict__ vb,
    bf16_t* __restrict__ Qb, bf16_t* __restrict__ XVb)
{
    __shared__ __align__(16) bf16_t fusb[16][136];   // 272B row stride -> 2-way max (free)
    int tid = threadIdx.x;
    int w = tid >> 6, l = tid & 63;
    int p0 = blockIdx.x * 16;
    int bb = p0 / NN, n0 = p0 % NN;

#pragma unroll
    for (int i = 0; i < 4; ++i) {
        int pt = i * 4 + w;
        int n = n0 + pt;
        float x = pts_img[(size_t)(p0 + pt) * 2 + 0];
        float y = pts_img[(size_t)(p0 + pt) * 2 + 1];
        float ix = (x + 1.f) * 0.5f * WW - 0.5f;
        float iy = (y + 1.f) * 0.5f * HH - 0.5f;
        float x0 = floorf(ix), y0 = floorf(iy);
        float wx1 = ix - x0, wx0 = 1.f - wx1;
        float wy1 = iy - y0, wy0 = 1.f - wy1;
        int xi0 = (int)x0, yi0 = (int)y0;
        const float* base = imgT + (size_t)bb * (HH * WW) * 64 + l;
        float iv = 0.f;
#pragma unroll
        for (int cr = 0; cr < 4; ++cr) {
            int xi = xi0 + (cr & 1), yi = yi0 + (cr >> 1);
            float wgt = ((cr & 1) ? wx1 : wx0) * ((cr >> 1) ? wy1 : wy0);
            bool v = (xi >= 0) & (xi <= WW - 1) & (yi >= 0) & (yi <= HH - 1);
            int cx = min(max(xi, 0), WW - 1), cy = min(max(yi, 0), HH - 1);
            float s = base[((size_t)cy * WW + cx) * 64];
            iv += (v ? s : 0.f) * wgt;
        }
        float pv = pfeat[((size_t)bb * CP + l) * NN + n];
        fusb[pt][l] = (bf16_t)iv;
        fusb[pt][64 + l] = (bf16_t)pv;
    }
    __syncthreads();

    int g = l >> 4, c16 = l & 15;
    f32x4 z = {0.f, 0.f, 0.f, 0.f};
    if (w < 2) {
        const float* wr = qkw + (size_t)(w * 16 + c16) * 128;
        f32x4 acc = z;
#pragma unroll
        for (int kk = 0; kk < 4; ++kk) {
            float4 a0 = *(const float4*)&wr[kk * 32 + 4 * g];
            float4 a1 = *(const float4*)&wr[kk * 32 + 16 + 4 * g];
            bf16x8 af = pack8(a0.x, a0.y, a0.z, a0.w, a1.x, a1.y, a1.z, a1.w);
            bf16x8 bfr = ld_av(&fusb[c16][kk * 32 + 4 * g]);
            acc = __builtin_amdgcn_mfma_f32_16x16x32_bf16(af, bfr, acc, 0, 0, 0);
        }
        bf16x4 qo;
#pragma unroll
        for (int r = 0; r < 4; ++r) qo[r] = (bf16_t)(acc[r] * SQ_L2E);
        *(bf16x4*)&Qb[((size_t)bb * NN + n0 + c16) * DD + w * 16 + 4 * g] = qo;
    } else {
        int vh = w - 2;
        const float* wrA = vw + (size_t)(vh * 32 + c16) * 64;
        const float* wrB = vw + (size_t)(vh * 32 + 16 + c16) * 64;
        f32x4 accA = z, accB = z;
#pragma unroll
        for (int kk = 0; kk < 2; ++kk) {
            bf16x8 bfr = ld_av(&fusb[c16][64 + kk * 32 + 4 * g]);
            float4 a0 = *(const float4*)&wrA[kk * 32 + 4 * g];
            float4 a1 = *(const float4*)&wrA[kk * 32 + 16 + 4 * g];
            accA = __builtin_amdgcn_mfma_f32_16x16x32_bf16(
                pack8(a0.x, a0.y, a0.z, a0.w, a1.x, a1.y, a1.z, a1.w), bfr, accA, 0, 0, 0);
            a0 = *(const float4*)&wrB[kk * 32 + 4 * g];
            a1 = *(const float4*)&wrB[kk * 32 + 16 + 4 * g];
            accB = __builtin_amdgcn_mfma_f32_16x16x32_bf16(
                pack8(a0.x, a0.y, a0.z, a0.w, a1.x, a1.y, a1.z, a1.w), bfr, accB, 0, 0, 0);
        }
#pragma unroll
        for (int r = 0; r < 4; ++r) {
            int oA = vh * 32 + 4 * g + r;
            int oB = oA + 16;
            XVb[((size_t)bb * CP + oA) * NN + n0 + c16] = (bf16_t)(accA[r] + vb[oA]);
            XVb[((size_t)bb * CP + oB) * NN + n0 + c16] = (bf16_t)(accB[r] + vb[oB]);
        }
    }
}

// K2: rowsum[n] = sum_m exp2(E[n,m]) (no max; exp2 headroom). m-split + atomics.
__global__ __launch_bounds__(256) void k_rowsum(
    const bf16_t* __restrict__ Qb, float* __restrict__ rowsumG)
{
    int b = blockIdx.z;
    int n0 = blockIdx.x * 64;
    int mchunk = blockIdx.y * (NN / SPLITM);
    int tid = threadIdx.x;
    int wv = tid >> 6, l = tid & 63;
    int g = l >> 4, c16 = l & 15;
    const bf16x8* Qv = (const bf16x8*)(Qb + (size_t)b * NN * DD);
    f32x4 z = {0.f, 0.f, 0.f, 0.f};

    bf16x8 A0 = Qv[(size_t)(n0 +  0 + c16) * 4 + g];
    bf16x8 A1 = Qv[(size_t)(n0 + 16 + c16) * 4 + g];
    bf16x8 A2 = Qv[(size_t)(n0 + 32 + c16) * 4 + g];
    bf16x8 A3 = Qv[(size_t)(n0 + 48 + c16) * 4 + g];

    float rs[4][4];
#pragma unroll
    for (int a = 0; a < 4; ++a)
#pragma unroll
        for (int r = 0; r < 4; ++r) rs[a][r] = 0.f;

    int mbase = mchunk + wv * 64;
    bf16x8 Bn0 = Qv[(size_t)(mbase +  0 + c16) * 4 + g];
    bf16x8 Bn1 = Qv[(size_t)(mbase + 16 + c16) * 4 + g];
    bf16x8 Bn2 = Qv[(size_t)(mbase + 32 + c16) * 4 + g];
    bf16x8 Bn3 = Qv[(size_t)(mbase + 48 + c16) * 4 + g];

    const int NIT = NN / SPLITM / 256;  // 4
    for (int it = 0; it < NIT; ++it) {
        bf16x8 B0 = Bn0, B1 = Bn1, B2 = Bn2, B3 = Bn3;
        int mnext = mbase + 256;
        if (it + 1 < NIT) {
            Bn0 = Qv[(size_t)(mnext +  0 + c16) * 4 + g];
            Bn1 = Qv[(size_t)(mnext + 16 + c16) * 4 + g];
            Bn2 = Qv[(size_t)(mnext + 32 + c16) * 4 + g];
            Bn3 = Qv[(size_t)(mnext + 48 + c16) * 4 + g];
        }
#define ROWSTEP(Aa, a)                                                        \
        {                                                                     \
            f32x4 e0 = __builtin_amdgcn_mfma_f32_16x16x32_bf16(Aa, B0, z, 0, 0, 0); \
            f32x4 e1 = __builtin_amdgcn_mfma_f32_16x16x32_bf16(Aa, B1, z, 0, 0, 0); \
            f32x4 e2 = __builtin_amdgcn_mfma_f32_16x16x32_bf16(Aa, B2, z, 0, 0, 0); \
            f32x4 e3 = __builtin_amdgcn_mfma_f32_16x16x32_bf16(Aa, B3, z, 0, 0, 0); \
            _Pragma("unroll")                                                 \
            for (int r = 0; r < 4; ++r)                                       \
                rs[a][r] += (fexp2(e0[r]) + fexp2(e1[r])) + (fexp2(e2[r]) + fexp2(e3[r])); \
        }
        ROWSTEP(A0, 0) ROWSTEP(A1, 1) ROWSTEP(A2, 2) ROWSTEP(A3, 3)
#undef ROWSTEP
        mbase = mnext;
    }
#pragma unroll
    for (int a = 0; a < 4; ++a)
#pragma unroll
        for (int r = 0; r < 4; ++r) {
            float v = rs[a][r];
            v += __shfl_xor(v, 1);
            v += __shfl_xor(v, 2);
            v += __shfl_xor(v, 4);
            v += __shfl_xor(v, 8);
            if (c16 == 0)
                atomicAdd(&rowsumG[(size_t)b * NN + n0 + 16 * a + 4 * g + r], v);
        }
}

// K2b: XVs = XV * irs[n], written in b128-frag layout: within each 256B chunk,
// slot(q4,g,h)=q4*64+g*16+h*8 holds k = q4*32+h*16+4g..+3; then byte ^= (c&7)<<4.
__global__ __launch_bounds__(256) void k_scale(
    const float* __restrict__ rowsumG, const bf16_t* __restrict__ XVb,
    bf16_t* __restrict__ XVs, bf16_t* __restrict__ irsb)
{
    int b = blockIdx.y;
    int cq = blockIdx.z;             // c-quarter
    int n = (blockIdx.x * 256 + threadIdx.x) * 4;
    float4 rs = *(const float4*)&rowsumG[(size_t)b * NN + n];
    float ir0 = 1.f / rs.x, ir1 = 1.f / rs.y, ir2 = 1.f / rs.z, ir3 = 1.f / rs.w;
    if (cq == 0) {
        bf16x4 iv;
        iv[0] = (bf16_t)ir0; iv[1] = (bf16_t)ir1; iv[2] = (bf16_t)ir2; iv[3] = (bf16_t)ir3;
        *(bf16x4*)&irsb[(size_t)b * NN + n] = iv;
    }
    const bf16_t* src = XVb + ((size_t)b * CP + cq * 16) * NN + n;
    char* dstbase = (char*)(XVs + ((size_t)b * CP + cq * 16) * NN);
    size_t nb = (size_t)n * 2;
    size_t hi = nb & ~(size_t)255;
    size_t lo = nb & 255;            // multiple of 8; bits: b3=k2,b4=k3,b5=k4(h),b6=k5,b7=k6
    size_t slot = (lo & 192) | (((lo >> 3) & 3) << 4) | (((lo >> 5) & 1) << 3);
#pragma unroll
    for (int c = 0; c < 16; ++c) {
        bf16x4 v = *(const bf16x4*)&src[(size_t)c * NN];
        bf16x4 o;
        o[0] = (bf16_t)((float)v[0] * ir0);
        o[1] = (bf16_t)((float)v[1] * ir1);
        o[2] = (bf16_t)((float)v[2] * ir2);
        o[3] = (bf16_t)((float)v[3] * ir3);
        size_t sb = hi | (slot ^ ((size_t)(c & 7) << 4));
        *(bf16x4*)(dstbase + (size_t)c * NN * 2 + sb) = o;
    }
}

// stage one 128-n XVs tile (64 rows x 256B, pre-swizzled source, linear dest) into LDS
__device__ __forceinline__ void stage_tile(const char* xvbase, int n0, char* ldsbuf, int wv, int l) {
#pragma unroll
    for (int k = 0; k < 2; ++k) {
        int R0 = k * 32 + wv * 4;          // 8 waves x 2 calls = rows 0..63
        int row = R0 + (l >> 4);
        const char* g = xvbase + (size_t)row * (NN * 2) + (size_t)n0 * 2 + (size_t)(l & 15) * 16;
        gload_lds16(g, ldsbuf + R0 * 256);
    }
}

// K3: LDS-staged main loop, 2-deep energy pipeline + counted-vmcnt barrier.
// PV A-frag is now ONE ds_read_b128 per ci (b128-frag XVs layout).
__global__ __launch_bounds__(512, 4) void k_attn(
    const bf16_t* __restrict__ Qb, const bf16_t* __restrict__ XVs,
    const bf16_t* __restrict__ irsb,
    bf16_t* __restrict__ part, float* __restrict__ cpart)
{
    __shared__ __align__(16) char lds[4 * 64 * 72 * 2];  // 36864B
    __shared__ float csL[4 * 64];

    int b = blockIdx.z;
    int m0 = blockIdx.x * 64;
    int chunk = blockIdx.y;
    int tid = threadIdx.x;
    int wv = tid >> 6, l = tid & 63;
    int g = l >> 4, c16 = l & 15;
    int q4 = wv & 3;        // n-split
    int jh = wv >> 2;       // m-half

    const bf16x8* Qv = (const bf16x8*)(Qb + (size_t)b * NN * DD);
    const char* xvbase = (const char*)(XVs + (size_t)b * CP * NN);
    const bf16_t* irow = irsb + (size_t)b * NN;

    bf16x8 bqA = Qv[(size_t)(m0 + jh * 32 + c16) * 4 + g];
    bf16x8 bqB = Qv[(size_t)(m0 + jh * 32 + 16 + c16) * 4 + g];

    f32x4 z = {0.f, 0.f, 0.f, 0.f};
    f32x4 acc[4][2];
    f32x4 acsA = z, acsB = z;
#pragma unroll
    for (int ci = 0; ci < 4; ++ci) { acc[ci][0] = z; acc[ci][1] = z; }

    const int NT = (NN / SPLITN) / 128;   // 32 tiles
    int nbase = chunk * (NN / SPLITN);

    stage_tile(xvbase, nbase, lds, wv, l);
    int nw0 = nbase + q4 * 32;
    bf16x8 aN0 = Qv[(size_t)(nw0 + c16) * 4 + g];
    bf16x8 aN1 = Qv[(size_t)(nw0 + 16 + c16) * 4 + g];
    bf16x8 cifC = ld_av(irow + nw0 + 4 * g);

    f32x4 EA0 = __builtin_amdgcn_mfma_f32_16x16x32_bf16(aN0, bqA, z, 0, 0, 0);
    f32x4 EA1 = __builtin_amdgcn_mfma_f32_16x16x32_bf16(aN1, bqA, z, 0, 0, 0);
    f32x4 EB0 = __builtin_amdgcn_mfma_f32_16x16x32_bf16(aN0, bqB, z, 0, 0, 0);
    f32x4 EB1 = __builtin_amdgcn_mfma_f32_16x16x32_bf16(aN1, bqB, z, 0, 0, 0);

    int nw1 = nbase + 128 + q4 * 32;
    aN0 = Qv[(size_t)(nw1 + c16) * 4 + g];
    aN1 = Qv[(size_t)(nw1 + 16 + c16) * 4 + g];
    bf16x8 cifN = ld_av(irow + nw1 + 4 * g);
    __syncthreads();

    const int pv_off = (q4 * 64 + g * 16) ^ ((c16 & 7) << 4);   // 16B-aligned b128 slot

    for (int t = 0; t < NT; ++t) {
        char* buf = lds + (t & 1) * 16384;
        if (t + 1 < NT)
            stage_tile(xvbase, nbase + (t + 1) * 128, lds + ((t + 1) & 1) * 16384, wv, l);

        bf16x8 bpA = pack8(fexp2(EA0[0]), fexp2(EA0[1]), fexp2(EA0[2]), fexp2(EA0[3]),
                           fexp2(EA1[0]), fexp2(EA1[1]), fexp2(EA1[2]), fexp2(EA1[3]));
        bf16x8 bpB = pack8(fexp2(EB0[0]), fexp2(EB0[1]), fexp2(EB0[2]), fexp2(EB0[3]),
                           fexp2(EB1[0]), fexp2(EB1[1]), fexp2(EB1[2]), fexp2(EB1[3]));

        if (t + 1 < NT) {
            EA0 = __builtin_amdgcn_mfma_f32_16x16x32_bf16(aN0, bqA, z, 0, 0, 0);
            EA1 = __builtin_amdgcn_mfma_f32_16x16x32_bf16(aN1, bqA, z, 0, 0, 0);
            EB0 = __builtin_amdgcn_mfma_f32_16x16x32_bf16(aN0, bqB, z, 0, 0, 0);
            EB1 = __builtin_amdgcn_mfma_f32_16x16x32_bf16(aN1, bqB, z, 0, 0, 0);
        }
        bf16x8 cifU = cifC;
        {
            int nw2 = (t + 2 < NT) ? (nbase + (t + 2) * 128 + q4 * 32) : (nbase + q4 * 32);
            aN0 = Qv[(size_t)(nw2 + c16) * 4 + g];
            aN1 = Qv[(size_t)(nw2 + 16 + c16) * 4 + g];
            cifC = cifN;
            cifN = ld_av(irow + nw2 + 4 * g);
        }

        __builtin_amdgcn_s_setprio(1);
        acsA = __builtin_amdgcn_mfma_f32_16x16x32_bf16(cifU, bpA, acsA, 0, 0, 0);
        acsB = __builtin_amdgcn_mfma_f32_16x16x32_bf16(cifU, bpB, acsB, 0, 0, 0);
#pragma unroll
        for (int ci = 0; ci < 4; ++ci) {
            bf16x8 xv = *(const bf16x8*)(buf + (16 * ci + c16) * 256 + pv_off);
            acc[ci][0] = __builtin_amdgcn_mfma_f32_16x16x32_bf16(xv, bpA, acc[ci][0], 0, 0, 0);
            acc[ci][1] = __builtin_amdgcn_mfma_f32_16x16x32_bf16(xv, bpB, acc[ci][1], 0, 0, 0);
        }
        __builtin_amdgcn_s_setprio(0);

        asm volatile("s_waitcnt vmcnt(4)" ::: "memory");
        __builtin_amdgcn_s_barrier();
    }

    // ---- epilogue ----
    __syncthreads();
    if (l < 16) {
        csL[q4 * 64 + 16 * (2 * jh + 0) + l] = acsA[0];
        csL[q4 * 64 + 16 * (2 * jh + 1) + l] = acsB[0];
    }
    bf16_t* epi = (bf16_t*)lds;   // [4 nsplit][64 cc][72 mm] bf16
#pragma unroll
    for (int ci = 0; ci < 4; ++ci)
#pragma unroll
        for (int jj = 0; jj < 2; ++jj)
#pragma unroll
            for (int r = 0; r < 4; ++r) {
                int cc = 16 * ci + 4 * g + r;
                int mm = jh * 32 + jj * 16 + c16;
                epi[((size_t)q4 * 64 + cc) * 72 + mm] = (bf16_t)acc[ci][jj][r];
            }
    __syncthreads();
    {
        int c = tid >> 3, m8 = (tid & 7) * 8;
        float s[8] = {0.f,0.f,0.f,0.f,0.f,0.f,0.f,0.f};
#pragma unroll
        for (int q = 0; q < 4; ++q) {
            bf16x8 v = *(const bf16x8*)&epi[((size_t)q * 64 + c) * 72 + m8];
#pragma unroll
            for (int i = 0; i < 8; ++i) s[i] += (float)v[i];
        }
        bf16x8 o;
#pragma unroll
        for (int i = 0; i < 8; ++i) o[i] = (bf16_t)s[i];
        *(bf16x8*)&part[(((size_t)chunk * BB + b) * CP + c) * NN + m0 + m8] = o;
    }
    if (tid < 64) {
        float cp = csL[tid] + csL[64 + tid] + csL[128 + tid] + csL[192 + tid];
        cpart[((size_t)chunk * BB + b) * NN + m0 + tid] = cp;
    }
}

// K4: tile kernel: combine partials + L1 renorm + T in LDS + t-conv (f32 VALU) + Y. No atomics.
__global__ __launch_bounds__(256) void k_post(
    const bf16_t* __restrict__ part, const float* __restrict__ cpart,
    const float* __restrict__ pfeat, const float* __restrict__ tw,
    const float* __restrict__ tb, float* __restrict__ Y)
{
    __shared__ float Tl[64][66];    // [c][n]
    __shared__ float twt[64][68];   // [c][o], 16B-aligned rows (272B)
    int tid = threadIdx.x;
    int b = blockIdx.y;
    int n0 = blockIdx.x * 64;
    int nl = tid & 63;
    int grp = tid >> 6;             // 0..3

    for (int i = tid; i < 64 * 64; i += 256)
        twt[i & 63][i >> 6] = tw[i];

    float cs = 0.f;
#pragma unroll
    for (int sp = 0; sp < SPLITN; ++sp)
        cs += cpart[((size_t)sp * BB + b) * NN + n0 + nl];
    float ic = 1.f / (1e-9f + cs);
#pragma unroll
    for (int k = 0; k < 16; ++k) {
        int c = k * 4 + grp;
        float xr = 0.f;
#pragma unroll
        for (int sp = 0; sp < SPLITN; ++sp)
            xr += (float)part[(((size_t)sp * BB + b) * CP + c) * NN + n0 + nl];
        Tl[c][nl] = pfeat[((size_t)b * CP + c) * NN + n0 + nl] - xr * ic;
    }
    __syncthreads();

    float y0 = tb[grp * 16 + 0], y1 = tb[grp * 16 + 1], y2 = tb[grp * 16 + 2], y3 = tb[grp * 16 + 3];
    float y4 = tb[grp * 16 + 4], y5 = tb[grp * 16 + 5], y6 = tb[grp * 16 + 6], y7 = tb[grp * 16 + 7];
    float y8 = tb[grp * 16 + 8], y9 = tb[grp * 16 + 9], yA = tb[grp * 16 +10], yB = tb[grp * 16 +11];
    float yC = tb[grp * 16 +12], yD = tb[grp * 16 +13], yE = tb[grp * 16 +14], yF = tb[grp * 16 +15];
#pragma unroll 4
    for (int c = 0; c < 64; ++c) {
        float t = Tl[c][nl];
        const float4* wr = (const float4*)&twt[c][grp * 16];
        float4 w0 = wr[0], w1 = wr[1], w2 = wr[2], w3 = wr[3];
        y0 += w0.x * t; y1 += w0.y * t; y2 += w0.z * t; y3 += w0.w * t;
        y4 += w1.x * t; y5 += w1.y * t; y6 += w1.z * t; y7 += w1.w * t;
        y8 += w2.x * t; y9 += w2.y * t; yA += w2.z * t; yB += w2.w * t;
        yC += w3.x * t; yD += w3.y * t; yE += w3.z * t; yF += w3.w * t;
    }
    float* yb = Y + ((size_t)b * CP + grp * 16) * NN + n0 + nl;
    yb[0 * NN] = y0;  yb[1 * NN] = y1;  yb[2 * NN] = y2;  yb[3 * NN] = y3;
    yb[4 * NN] = y4;  yb[5 * NN] = y5;  yb[6 * NN] = y6;  yb[7 * NN] = y7;
    yb[8 * NN] = y8;  yb[9 * NN] = y9;  yb[10 * NN] = yA; yb[11 * NN] = yB;
    yb[12 * NN] = yC; yb[13 * NN] = yD; yb[14 * NN] = yE; yb[15 * NN] = yF;
}

// K4b: BN stats from Y: block = (n-chunk 2048, o, b); wave reduce + few atomics
__global__ __launch_bounds__(256) void k_bnstat(
    const float* __restrict__ Y, float* __restrict__ bnred)
{
    __shared__ float red[8];
    int tid = threadIdx.x;
    int o = blockIdx.y, b = blockIdx.z;
    const float* row = Y + ((size_t)b * CP + o) * NN + blockIdx.x * 2048 + tid * 8;
    float4 a = *(const float4*)row;
    float4 c4 = *(const float4*)(row + 4);
    float sv = ((a.x + a.y) + (a.z + a.w)) + ((c4.x + c4.y) + (c4.z + c4.w));
    float sq = ((a.x*a.x + a.y*a.y) + (a.z*a.z + a.w*a.w))
             + ((c4.x*c4.x + c4.y*c4.y) + (c4.z*c4.z + c4.w*c4.w));
#pragma unroll
    for (int off = 1; off < 64; off <<= 1) {
        sv += __shfl_xor(sv, off);
        sq += __shfl_xor(sq, off);
    }
    int wv = tid >> 6;
    if ((tid & 63) == 0) { red[wv] = sv; red[4 + wv] = sq; }
    __syncthreads();
    if (tid == 0) {
        atomicAdd(&bnred[o], red[0] + red[1] + red[2] + red[3]);
        atomicAdd(&bnred[64 + o], red[4] + red[5] + red[6] + red[7]);
    }
}

// K5: BN finalize + ReLU + residual (float4 vectorized)
__global__ __launch_bounds__(256) void k_final(
    const float* __restrict__ Y, const float* __restrict__ pfeat,
    const float* __restrict__ gamma, const float* __restrict__ beta,
    const float* __restrict__ bnred, float* __restrict__ out)
{
    int idx4 = blockIdx.x * 256 + threadIdx.x;   // flat over [B][CP][NN]/4
    int o = ((idx4 * 4) / NN) & (CP - 1);
    const float invcnt = 1.f / (float)(BB * NN);
    float mean = bnred[o] * invcnt;
    float var = bnred[64 + o] * invcnt - mean * mean;
    float sc = gamma[o] * rsqrtf(var + 1e-5f);
    float sh = beta[o] - mean * sc;
    float4 y = ((const float4*)Y)[idx4];
    float4 p = ((const float4*)pfeat)[idx4];
    float4 r;
    r.x = p.x + fmaxf(y.x * sc + sh, 0.f);
    r.y = p.y + fmaxf(y.y * sc + sh, 0.f);
    r.z = p.z + fmaxf(y.z * sc + sh, 0.f);
    r.w = p.w + fmaxf(y.w * sc + sh, 0.f);
    ((float4*)out)[idx4] = r;
}

extern "C" void kernel_launch(void* const* d_in, const int* in_sizes, int n_in,
                              void* d_out, int out_size, void* d_ws, size_t ws_size,
                              hipStream_t stream) {
    const float* pts_img = (const float*)d_in[0];
    const float* img     = (const float*)d_in[1];
    const float* pfeat   = (const float*)d_in[2];
    const float* qkw     = (const float*)d_in[3];
    const float* vw      = (const float*)d_in[4];
    const float* vb      = (const float*)d_in[5];
    const float* tw      = (const float*)d_in[6];
    const float* tb      = (const float*)d_in[7];
    const float* gamma   = (const float*)d_in[8];
    const float* beta    = (const float*)d_in[9];

    // workspace layout (bytes), total ~35.3 MB
    char* base = (char*)d_ws;
    bf16_t* Qb      = (bf16_t*)(base);                  // 1,048,576   [B][N][32]
    bf16_t* XVb     = (bf16_t*)(base + 1048576);        // 2,097,152   [B][64][N]
    bf16_t* XVs     = (bf16_t*)(base + 3145728);        // 2,097,152   [B][64][N] b128-frag swizzled
    float*  rowsumG = (float*)(base + 5251072);         // 65,536      [B][N]
    float*  bn      = (float*)(base + 5316608);         // 512
    bf16_t* irsb    = (bf16_t*)(base + 5317120);        // 32,768      [B][N] bf16
    float*  cpart   = (float*)(base + 5349888);         // 131,072     [SPLITN][B][N]
    float*  Y       = (float*)(base + 5874176);         // 4,194,304   [B][64][N]
    bf16_t* part    = (bf16_t*)(base + 10068480);       // 4,194,304   [SPLITN][B][64][N] bf16
    float*  imgT    = (float*)(base + 26845696);        // 8,388,608   [B][HW][64]

    hipMemsetAsync(base + 5251072, 0, 66048, stream);  // rowsumG + bn (contiguous)
    k_timg<<<dim3((HH * WW) / 64, BB), 256, 0, stream>>>(img, imgT);
    k_fuse<<<(BB * NN) / 16, 256, 0, stream>>>(pts_img, imgT, pfeat, qkw, vw, vb, Qb, XVb);
    k_rowsum<<<dim3(NN / 64, SPLITM, BB), 256, 0, stream>>>(Qb, rowsumG);
    k_scale<<<dim3(NN / 1024, BB, 4), 256, 0, stream>>>(rowsumG, XVb, XVs, irsb);
    k_attn<<<dim3(NN / 64, SPLITN, BB), 512, 0, stream>>>(Qb, XVs, irsb, part, cpart);
    k_post<<<dim3(NN / 64, BB), 256, 0, stream>>>(part, cpart, pfeat, tw, tb, Y);
    k_bnstat<<<dim3(NN / 2048, CP, BB), 256, 0, stream>>>(Y, bn);
    k_final<<<(BB * CP * NN) / 1024, 256, 0, stream>>>(Y, pfeat, gamma, beta, bn, (float*)d_out);
}